// Round 12
// baseline (353.339 us; speedup 1.0000x reference)
//
#include <hip/hip_runtime.h>
#include <hip/hip_bf16.h>

typedef __bf16 bf16_t;
typedef __bf16 bf16x4_t __attribute__((ext_vector_type(4)));
typedef __bf16 bf16x8_t __attribute__((ext_vector_type(8)));
typedef float  f32x4_t  __attribute__((ext_vector_type(4)));

#define B_   8
#define LQ_  512
#define LKV_ 512
#define D_   1024
#define H_   16
#define DH_  64
#define FF_  4096

__device__ __forceinline__ f32x4_t mfma16(bf16x8_t a, bf16x8_t b, f32x4_t c) {
    return __builtin_amdgcn_mfma_f32_16x16x32_bf16(a, b, c, 0, 0, 0);
}

__device__ __forceinline__ void gload_lds16(const bf16_t* g, bf16_t* l) {
    __builtin_amdgcn_global_load_lds(
        (const __attribute__((address_space(1))) void*)g,
        (__attribute__((address_space(3))) void*)l, 16, 0, 0);
}

// bijective XCD chunking (requires nwg % 8 == 0)
__device__ __forceinline__ int xcd_swz(int pid, int nwg) {
    return (pid & 7) * (nwg >> 3) + (pid >> 3);
}

// fast GELU: h * sigmoid(1.702 h).
__device__ __forceinline__ float gelu_fast(float h) {
    const float e = exp2f(h * -2.45546696f);     // exp(-1.702 h)
    return h * __builtin_amdgcn_rcpf(1.f + e);
}

// ---------------------------------------------------------------------------
// fused f32 -> bf16 convert for all 8 tensors (one launch).
// ---------------------------------------------------------------------------
__global__ __launch_bounds__(256)
void cvt_all_kernel(const float* __restrict__ q,  const float* __restrict__ kv,
                    const float* __restrict__ Wq, const float* __restrict__ Wk,
                    const float* __restrict__ Wv, const float* __restrict__ Wm,
                    const float* __restrict__ Wf1,const float* __restrict__ Wf2,
                    bf16_t* __restrict__ dq, bf16_t* __restrict__ dW,
                    bf16_t* __restrict__ dF) {
    const int i = blockIdx.x * 256 + threadIdx.x;    // grid 20480 -> i < 5242880
    const float* s; bf16_t* d; int j;
    if (i < 1048576)      { s = q;   d = dq;           j = i; }
    else if (i < 2097152) { s = kv;  d = dq + 4194304; j = i - 1048576; }
    else if (i < 2359296) { s = Wq;  d = dW;           j = i - 2097152; }
    else if (i < 2621440) { s = Wk;  d = dW + 1048576; j = i - 2359296; }
    else if (i < 2883584) { s = Wv;  d = dW + 2097152; j = i - 2621440; }
    else if (i < 3145728) { s = Wm;  d = dW + 3145728; j = i - 2883584; }
    else if (i < 4194304) { s = Wf1; d = dF;           j = i - 3145728; }
    else                  { s = Wf2; d = dF + 4194304; j = i - 4194304; }
    const float4 v = ((const float4*)s)[j];
    bf16x4_t o;
    o[0] = (bf16_t)v.x; o[1] = (bf16_t)v.y; o[2] = (bf16_t)v.z; o[3] = (bf16_t)v.w;
    ((bf16x4_t*)d)[j] = o;
}

__global__ __launch_bounds__(256)
void pack3_kernel(const float* __restrict__ a, const float* __restrict__ b,
                  const float* __restrict__ c, float* __restrict__ o) {
    const int i = blockIdx.x * 256 + threadIdx.x;   // grid 4 -> i < 1024
    o[i] = a[i]; o[1024 + i] = b[i]; o[2048 + i] = c[i];
}

// ---------------------------------------------------------------------------
// Streaming log2 pre-pass: logmap[((b*512+q)*512+k)*16 + c] = bf16(log2(amap+eps))
// Pure load->log2->store, no dependent consumer: latency hides via TLP.
// Output is position-major so bias_mlp reads 32B/lane CONTIGUOUS.
// ---------------------------------------------------------------------------
__global__ __launch_bounds__(256)
void logmap_kernel(const float* __restrict__ amap, bf16_t* __restrict__ logmap) {
    const int t = threadIdx.x, lane = t & 63, w = t >> 6;
    const int posb = (blockIdx.x * 4 + w) * 64;
    const int b  = posb >> 18;
    const int q  = (posb >> 9) & 511;
    const int k0 = posb & 511;
    const float* src = amap + (size_t)(b * 16) * 263169 + (size_t)(q + 1) * 513 + (k0 + 1 + lane);
    bf16_t xr[16];
#pragma unroll
    for (int c = 0; c < 16; c++) {
        const float v = src[(size_t)c * 263169];
        xr[c] = (bf16_t)__log2f(v + 1e-6f);
    }
    bf16_t* dst = logmap + ((size_t)(b * 512 + q) * 512 + k0 + lane) * 16;
    *(bf16x8_t*)dst       = *(bf16x8_t*)&xr[0];
    *(bf16x8_t*)(dst + 8) = *(bf16x8_t*)&xr[8];
}

// ---------------------------------------------------------------------------
// AttentionBiasMLP via MFMA.  One wave handles 64 consecutive positions.
// Reads position-major bf16 logmap (contiguous 32B/lane).  Xs (48B rows) and
// Hs (80B rows) are time-disjoint, ALIASED -> 20 KB/block.
// W1 is pre-scaled by ln2 (logmap holds log2 values).
// ---------------------------------------------------------------------------
__global__ __launch_bounds__(256)
void bias_mlp_mfma(const bf16_t* __restrict__ logmap,
                   const float* __restrict__ Wc1, const float* __restrict__ bc1,
                   const float* __restrict__ Wc2, const float* __restrict__ bc2,
                   bf16_t* __restrict__ biasb) {
    __shared__ __align__(16) char lds[4][5120];
    const int t = threadIdx.x, lane = t & 63, w = t >> 6;
    const int l15 = lane & 15, lg = lane >> 4;
    char* Xs = lds[w];           // rows of 48 B, bytes [0, 3072)
    char* Hs = lds[w];           // rows of 80 B, bytes [0, 5120)  (aliased)

    bf16x8_t b1f[2], b2f;
    f32x4_t bc1v[2];
#pragma unroll
    for (int ot = 0; ot < 2; ot++) {
        bf16x8_t v;
#pragma unroll
        for (int i = 0; i < 8; i++) {
            const int kk = (lg * 8 + i) & 15;
            const float wv = Wc1[(ot * 16 + l15) * 16 + kk] * 0.69314718055994531f;
            v[i] = (lg < 2) ? (bf16_t)wv : (bf16_t)0.f;
        }
        b1f[ot] = v;
        const float bb = bc1[ot * 16 + l15];
        bc1v[ot] = f32x4_t{bb, bb, bb, bb};
    }
    {
        bf16x8_t v;
#pragma unroll
        for (int i = 0; i < 8; i++) v[i] = (bf16_t)Wc2[l15 * 32 + lg * 8 + i];
        b2f = v;
    }
    const float bc2s = bc2[l15];
    const f32x4_t cinit2 = f32x4_t{bc2s, bc2s, bc2s, bc2s};

    const int posb = (blockIdx.x * 4 + w) * 64;
    const int b  = posb >> 18;
    const int q  = (posb >> 9) & 511;
    const int k0 = posb & 511;

    // contiguous 32B read per lane
    const bf16_t* src = logmap + ((size_t)(b * 512 + q) * 512 + k0 + lane) * 16;
    *(bf16x8_t*)(Xs + lane * 48)      = *(const bf16x8_t*)src;
    *(bf16x8_t*)(Xs + lane * 48 + 16) = *(const bf16x8_t*)(src + 8);

    const int lgm16 = (lg & 1) * 16;
    f32x4_t h1[4][2];
#pragma unroll
    for (int p = 0; p < 4; p++) {
        const bf16x8_t a1 = *(const bf16x8_t*)(Xs + (p * 16 + l15) * 48 + lgm16);
#pragma unroll
        for (int ot = 0; ot < 2; ot++)
            h1[p][ot] = mfma16(a1, b1f[ot], bc1v[ot]);
    }
    // fence: all Xs reads retired before Hs (aliased) writes below
    asm volatile("s_waitcnt lgkmcnt(0)" ::: "memory");
    __builtin_amdgcn_sched_barrier(0);

#pragma unroll
    for (int p = 0; p < 4; p++)
#pragma unroll
        for (int ot = 0; ot < 2; ot++)
#pragma unroll
            for (int r = 0; r < 4; r++) {
                const float g = gelu_fast(h1[p][ot][r]);
                *(bf16_t*)(Hs + (p * 16 + lg * 4 + r) * 80 + (ot * 16 + l15) * 2) = (bf16_t)g;
            }

    const size_t obase = ((size_t)(b * 16 + l15) * 512 + q) * 512 + k0;
#pragma unroll
    for (int p = 0; p < 4; p++) {
        const bf16x8_t a2 = *(const bf16x8_t*)(Hs + (p * 16 + l15) * 80 + lg * 16);
        const f32x4_t o2 = mfma16(a2, b2f, cinit2);
        bf16x4_t ov;
#pragma unroll
        for (int r = 0; r < 4; r++) ov[r] = (bf16_t)o2[r];
        *(bf16x4_t*)&biasb[obase + p * 16 + lg * 4] = ov;
    }
}

// ---------------------------------------------------------------------------
// 128^2 bf16 GEMM (3-slot pipeline) -- out-proj / FFN2 (N=1024 shapes).
// LDS chunk-swizzle s(r)=r&3 both-sides.
// ---------------------------------------------------------------------------
template <int EPI, bool SPLIT>
__global__ __launch_bounds__(256)
void gemm_bt(const bf16_t* __restrict__ A, const bf16_t* __restrict__ A2,
             const bf16_t* __restrict__ Bw,
             const float* __restrict__ bias,
             bf16_t* __restrict__ Cb, int M, int N, int Klen, int lda) {
    __shared__ __align__(16) bf16_t As[3][128 * 32];
    __shared__ __align__(16) bf16_t Bs[3][128 * 32];
    const int t = threadIdx.x, lane = t & 63, w = t >> 6;
    const int wr = w >> 1, wc = w & 1;
    const int ntn = N >> 7;
    const int nwg = (M >> 7) * ntn;
    const int wg  = xcd_swz((int)blockIdx.x, nwg);
    const int gsz = 8 * ntn;
    const int gid = wg / gsz;
    const int rem = wg - gid * gsz;
    const int tm  = gid * 8 + (rem & 7);
    const int tn  = rem >> 3;
    const int l15 = lane & 15, lg = lane >> 4;
    const int ks = SPLIT ? blockIdx.y : 0;
    const int koff = SPLIT ? ks * Klen : 0;

    const int r0 = t >> 2,          sk0 = (t & 3) ^ ((t >> 2) & 3);
    const int r1 = (t + 256) >> 2,  sk1 = (t & 3) ^ ((t >> 2) & 3);
    const int b0 = (w * 64) * 8;
    const int b1 = (256 + w * 64) * 8;
    const bf16_t* Abase0 = A  + (size_t)(tm * 128 + r0) * lda + koff + sk0 * 8;
    const bf16_t* Abase1 = A  + (size_t)(tm * 128 + r1) * lda + koff + sk1 * 8;
    const bf16_t* Bbase0 = Bw + (size_t)(tn * 128 + r0) * lda + koff + sk0 * 8;
    const bf16_t* Bbase1 = Bw + (size_t)(tn * 128 + r1) * lda + koff + sk1 * 8;

    f32x4_t acc[4][4];
#pragma unroll
    for (int i = 0; i < 4; i++)
#pragma unroll
        for (int j = 0; j < 4; j++) acc[i][j] = f32x4_t{0.f, 0.f, 0.f, 0.f};

    const int nk = Klen >> 5;

#define STAGE128(KT, S)                                 \
    do {                                                \
        const int _ko = (KT) * 32;                      \
        gload_lds16(Abase0 + _ko, &As[(S)][b0]);        \
        gload_lds16(Abase1 + _ko, &As[(S)][b1]);        \
        gload_lds16(Bbase0 + _ko, &Bs[(S)][b0]);        \
        gload_lds16(Bbase1 + _ko, &Bs[(S)][b1]);        \
    } while (0)

    STAGE128(0, 0);
    STAGE128(1, 1);

    const int rsw = l15 & 3;           // read-side row&3
    int cur = 0;
    for (int kt = 0; kt < nk; ++kt) {
        if (kt + 1 < nk) { asm volatile("s_waitcnt vmcnt(4)" ::: "memory"); }
        else             { asm volatile("s_waitcnt vmcnt(0)" ::: "memory"); }
        __syncthreads();
        if (kt + 2 < nk) {
            const int s2 = cur >= 1 ? cur - 1 : cur + 2;
            STAGE128(kt + 2, s2);
        }

        const bf16_t* Ac = As[cur];
        const bf16_t* Bc = Bs[cur];
        bf16x8_t af[4], bfv[4];
#pragma unroll
        for (int mt = 0; mt < 4; mt++)
            af[mt] = *(const bf16x8_t*)&Ac[(wr * 64 + mt * 16 + l15) * 32 + ((lg ^ rsw) * 8)];
#pragma unroll
        for (int nt = 0; nt < 4; nt++)
            bfv[nt] = *(const bf16x8_t*)&Bc[(wc * 64 + nt * 16 + l15) * 32 + ((lg ^ rsw) * 8)];
#pragma unroll
        for (int mt = 0; mt < 4; mt++)
#pragma unroll
            for (int nt = 0; nt < 4; nt++)
                acc[mt][nt] = mfma16(af[mt], bfv[nt], acc[mt][nt]);

        cur = cur < 2 ? cur + 1 : 0;
    }
#undef STAGE128

#pragma unroll
    for (int nt = 0; nt < 4; nt++) {
        const int col = tn * 128 + wc * 64 + nt * 16 + l15;
        float bv = bias[col];
        if (SPLIT && ks != 0) bv = 0.f;
#pragma unroll
        for (int mt = 0; mt < 4; mt++) {
#pragma unroll
            for (int r = 0; r < 4; r++) {
                const int row = tm * 128 + wr * 64 + mt * 16 + lg * 4 + r;
                float v = acc[mt][nt][r] + bv;
                if (EPI == 2) v = fmaxf(v, 0.f);
                if (SPLIT)
                    Cb[(size_t)ks * M * N + (size_t)row * N + col] = (bf16_t)v;
                else Cb[(size_t)row * N + col] = (bf16_t)v;
            }
        }
    }
}

// ---------------------------------------------------------------------------
// 256^2 BK=64 8-wave phase-split GEMM.  LDS chunk-swizzle s(r)=r&7 both-sides.
// EPI: 2 = relu bf16 out (FFN1);  3 = QKV fused (A per column block, Q*0.125)
// ---------------------------------------------------------------------------
template <int EPI>
__global__ __launch_bounds__(512, 1)
void gemm8p(const bf16_t* __restrict__ A, const bf16_t* __restrict__ A2,
            const bf16_t* __restrict__ Bw, const float* __restrict__ bias,
            bf16_t* __restrict__ Cb, int M, int N, int Klen, int lda) {
    __shared__ __align__(16) bf16_t As[2][256 * 64];   // 32 KB per buffer
    __shared__ __align__(16) bf16_t Bs[2][256 * 64];   // total LDS 128 KB
    const int t = threadIdx.x, lane = t & 63, w = t >> 6;     // 8 waves
    const int wr = w >> 2, wc = w & 3;                        // 2 x 4 wave grid
    const int l15 = lane & 15, lg = lane >> 4;
    const int ntn = N >> 8;
    const int nwg = (M >> 8) * ntn;
    const int wg  = xcd_swz((int)blockIdx.x, nwg);
    const int gsz = 8 * ntn;
    const int gid = wg / gsz;
    const int rem = wg - gid * gsz;
    const int tm  = gid * 8 + (rem & 7);
    const int tn  = rem >> 3;
    if (EPI == 3 && tn >= 4) A = A2;    // cols >= 1024 use kv input

    const int srow = w * 8 + (lane >> 3);
    const int scol = ((lane & 7) ^ (lane >> 3)) * 8;
    const bf16_t* Ag = A  + (size_t)(tm * 256 + srow) * lda + scol;
    const bf16_t* Bg = Bw + (size_t)(tn * 256 + srow) * lda + scol;
    const int ldsb = w * 512;

#define STAGE256(KT, S)                                                      \
    do {                                                                     \
        const size_t _ko = (size_t)(KT) * 64;                                \
        _Pragma("unroll")                                                    \
        for (int _i = 0; _i < 4; _i++) {                                     \
            gload_lds16(Ag + (size_t)(_i * 64) * lda + _ko,                  \
                        &As[(S)][_i * 4096 + ldsb]);                         \
            gload_lds16(Bg + (size_t)(_i * 64) * lda + _ko,                  \
                        &Bs[(S)][_i * 4096 + ldsb]);                         \
        }                                                                    \
    } while (0)

    f32x4_t acc[8][4];
#pragma unroll
    for (int i = 0; i < 8; i++)
#pragma unroll
        for (int j = 0; j < 4; j++) acc[i][j] = f32x4_t{0.f, 0.f, 0.f, 0.f};

    const int nk = Klen >> 6;          // K=1024 -> 16

    STAGE256(0, 0);
    STAGE256(1, 1);

    const int rsw = l15 & 7;           // read-side row&7
    for (int kt = 0; kt < nk; ++kt) {
        const int s = kt & 1;
        if (kt + 1 < nk) { asm volatile("s_waitcnt vmcnt(8)" ::: "memory"); }
        else             { asm volatile("s_waitcnt vmcnt(0)" ::: "memory"); }
        __builtin_amdgcn_s_barrier();            // barrier A: tile kt visible
        __builtin_amdgcn_sched_barrier(0);

#pragma unroll
        for (int q = 0; q < 4; q++) {            // quadrant (mh, nh)
            const int mh = q >> 1, nh = q & 1;
            bf16x8_t af[4][2], bfv[2][2];
#pragma unroll
            for (int mi = 0; mi < 4; mi++) {
                const int row = wr * 128 + (mh * 4 + mi) * 16 + l15;
#pragma unroll
                for (int kk = 0; kk < 2; kk++)
                    af[mi][kk] = *(const bf16x8_t*)&As[s][row * 64 + (((kk * 4 + lg) ^ rsw) * 8)];
            }
#pragma unroll
            for (int ni = 0; ni < 2; ni++) {
                const int row = wc * 64 + (nh * 2 + ni) * 16 + l15;
#pragma unroll
                for (int kk = 0; kk < 2; kk++)
                    bfv[ni][kk] = *(const bf16x8_t*)&Bs[s][row * 64 + (((kk * 4 + lg) ^ rsw) * 8)];
            }
            __builtin_amdgcn_s_setprio(1);
#pragma unroll
            for (int mi = 0; mi < 4; mi++)
#pragma unroll
                for (int ni = 0; ni < 2; ni++)
#pragma unroll
                    for (int kk = 0; kk < 2; kk++)
                        acc[mh * 4 + mi][nh * 2 + ni] =
                            mfma16(af[mi][kk], bfv[ni][kk], acc[mh * 4 + mi][nh * 2 + ni]);
            __builtin_amdgcn_s_setprio(0);
        }

        __builtin_amdgcn_sched_barrier(0);
        __builtin_amdgcn_s_barrier();            // barrier B: all reads retired
        __builtin_amdgcn_sched_barrier(0);
        if (kt + 2 < nk) STAGE256(kt + 2, s);    // refill freed buffer
    }
#undef STAGE256

    // epilogue
#pragma unroll
    for (int n = 0; n < 4; n++) {
        const int col = tn * 256 + wc * 64 + n * 16 + l15;
        const float bv = bias[col];
#pragma unroll
        for (int m = 0; m < 8; m++) {
#pragma unroll
            for (int r = 0; r < 4; r++) {
                const int row = tm * 256 + wr * 128 + m * 16 + lg * 4 + r;
                float v = acc[m][n][r] + bv;
                if (EPI == 2) v = fmaxf(v, 0.f);
                if (EPI == 3 && tn < 4) v *= 0.125f;
                if (EPI == 3)
                    Cb[(size_t)(col >> 10) * 4194304 + (size_t)row * 1024 + (col & 1023)] = (bf16_t)v;
                else
                    Cb[(size_t)row * N + col] = (bf16_t)v;
            }
        }
    }
}

// ---------------------------------------------------------------------------
// Flash attention with additive bias (unchanged).
// ---------------------------------------------------------------------------
__global__ __launch_bounds__(256)
void attn_kernel(const bf16_t* __restrict__ Qp, const bf16_t* __restrict__ Kp,
                 const bf16_t* __restrict__ Vp, const bf16_t* __restrict__ biasb,
                 bf16_t* __restrict__ ctx) {
    __shared__ __align__(16) bf16_t Qs[64 * 64];
    __shared__ __align__(16) bf16_t Ks[64 * 64];
    __shared__ __align__(16) bf16_t Vts[64 * 64];
    __shared__ __align__(16) bf16_t Ps[64 * 64];
    __shared__ __align__(16) bf16_t Bbs[64 * 64];

    const int bid = xcd_swz((int)blockIdx.x, 1024);
    const int qt = bid & 7, h = (bid >> 3) & 15, b = bid >> 7;
    const int t = threadIdx.x, lane = t & 63, w = t >> 6;
    const int l15 = lane & 15, lg = lane >> 4;

#pragma unroll
    for (int i = 0; i < 2; i++) {
        const int c = t + i * 256;
        const int row = c >> 3, cg = c & 7;
        const uint4 v = *(const uint4*)&Qp[(((size_t)(b * LQ_ + qt * 64 + row)) * H_ + h) * DH_ + cg * 8];
        *(uint4*)((char*)Qs + row * 128 + ((cg ^ (row & 7)) << 4)) = v;
    }
    __syncthreads();

    bf16x8_t aq[2];
    {
        const int rowq = w * 16 + l15;
#pragma unroll
        for (int kc = 0; kc < 2; kc++)
            aq[kc] = *(const bf16x8_t*)((const char*)Qs + rowq * 128 + (((kc * 4 + lg) ^ (rowq & 7)) << 4));
    }

    f32x4_t oacc[4];
#pragma unroll
    for (int i = 0; i < 4; i++) oacc[i] = f32x4_t{0.f, 0.f, 0.f, 0.f};
    float mrow[4] = {-1e30f, -1e30f, -1e30f, -1e30f};
    float lrow[4] = {0.f, 0.f, 0.f, 0.f};

    const bf16_t* bias_tile = biasb + ((size_t)(b * H_ + h) * LQ_ + qt * 64) * LKV_;

    for (int kt = 0; kt < 8; ++kt) {
        __syncthreads();
#pragma unroll
        for (int i = 0; i < 2; i++) {
            const int c = t + i * 256;
            const int row = c >> 3, cg = c & 7;
            const uint4 v = *(const uint4*)&Kp[(((size_t)(b * LKV_ + kt * 64 + row)) * H_ + h) * DH_ + cg * 8];
            *(uint4*)((char*)Ks + row * 128 + ((cg ^ (row & 7)) << 4)) = v;
        }
#pragma unroll
        for (int i = 0; i < 2; i++) {
            const int c = t + i * 256;
            const int row = c >> 3, cg = c & 7;
            const uint4 bv4 = *(const uint4*)&bias_tile[(size_t)row * LKV_ + kt * 64 + cg * 8];
            *(uint4*)&Bbs[row * 64 + cg * 8] = bv4;
        }
#pragma unroll
        for (int i = 0; i < 2; i++) {
            const int c = t + i * 256;
            const int k = c >> 3, dg = c & 7;
            const bf16x8_t vv = *(const bf16x8_t*)&Vp[(((size_t)(b * LKV_ + kt * 64 + k)) * H_ + h) * DH_ + dg * 8];
#pragma unroll
            for (int j = 0; j < 8; j++) {
                const int d = dg * 8 + j;
                *(bf16_t*)((char*)Vts + d * 128 + ((((k * 2) >> 4) ^ (d & 7)) << 4) + ((k * 2) & 15)) = vv[j];
            }
        }
        __syncthreads();

        f32x4_t sacc[4];
#pragma unroll
        for (int i = 0; i < 4; i++) sacc[i] = f32x4_t{0.f, 0.f, 0.f, 0.f};
#pragma unroll
        for (int nt = 0; nt < 4; nt++) {
            const int rowk = nt * 16 + l15;
#pragma unroll
            for (int kc = 0; kc < 2; kc++) {
                const bf16x8_t bk = *(const bf16x8_t*)((const char*)Ks + rowk * 128 + (((kc * 4 + lg) ^ (rowk & 7)) << 4));
                sacc[nt] = mfma16(aq[kc], bk, sacc[nt]);
            }
        }

        float esc[4];
#pragma unroll
        for (int r = 0; r < 4; r++) {
            const int qr = w * 16 + lg * 4 + r;
            float mx = -1e30f;
#pragma unroll
            for (int nt = 0; nt < 4; nt++) {
                const float bvv = (float)Bbs[qr * 64 + nt * 16 + l15];
                const float v = sacc[nt][r] + bvv;
                sacc[nt][r] = v;
                mx = fmaxf(mx, v);
            }
#pragma unroll
            for (int msk = 8; msk >= 1; msk >>= 1) mx = fmaxf(mx, __shfl_xor(mx, msk));
            const float mnew = fmaxf(mrow[r], mx);
            esc[r] = __expf(mrow[r] - mnew);
            mrow[r] = mnew;
            float rs = 0.f;
#pragma unroll
            for (int nt = 0; nt < 4; nt++) {
                const float p = __expf(sacc[nt][r] - mnew);
                sacc[nt][r] = p;
                rs += p;
            }
#pragma unroll
            for (int msk = 8; msk >= 1; msk >>= 1) rs += __shfl_xor(rs, msk);
            lrow[r] = lrow[r] * esc[r] + rs;
        }

#pragma unroll
        for (int r = 0; r < 4; r++) {
            const int prow = w * 16 + lg * 4 + r;
#pragma unroll
            for (int nt = 0; nt < 4; nt++) {
                const int pc2 = (nt * 16 + l15) * 2;
                *(bf16_t*)((char*)Ps + prow * 128 + (((pc2 >> 4) ^ (prow & 7)) << 4) + (pc2 & 15)) =
                    (bf16_t)sacc[nt][r];
            }
        }
        asm volatile("s_waitcnt lgkmcnt(0)" ::: "memory");
        __builtin_amdgcn_sched_barrier(0);

#pragma unroll
        for (int dt = 0; dt < 4; dt++)
#pragma unroll
            for (int r = 0; r < 4; r++) oacc[dt][r] *= esc[r];

        bf16x8_t pa[2];
        {
            const int rowp = w * 16 + l15;
#pragma unroll
            for (int kc = 0; kc < 2; kc++)
                pa[kc] = *(const bf16x8_t*)((const char*)Ps + rowp * 128 + (((kc * 4 + lg) ^ (rowp & 7)) << 4));
        }
#pragma unroll
        for (int dt = 0; dt < 4; dt++) {
            const int rowv = dt * 16 + l15;
#pragma unroll
            for (int kc = 0; kc < 2; kc++) {
                const bf16x8_t bv = *(const bf16x8_t*)((const char*)Vts + rowv * 128 + (((kc * 4 + lg) ^ (rowv & 7)) << 4));
                oacc[dt] = mfma16(pa[kc], bv, oacc[dt]);
            }
        }
    }

    float inv[4];
#pragma unroll
    for (int r = 0; r < 4; r++) inv[r] = __builtin_amdgcn_rcpf(lrow[r]);
#pragma unroll
    for (int dt = 0; dt < 4; dt++) {
#pragma unroll
        for (int r = 0; r < 4; r++) {
            const float v = oacc[dt][r] * inv[r];
            const int q = qt * 64 + w * 16 + lg * 4 + r;
            const int d = dt * 16 + l15;
            ctx[(((size_t)(b * LQ_ + q)) * H_ + h) * DH_ + d] = (bf16_t)v;
        }
    }
}

// ---------------------------------------------------------------------------
// out = LayerNorm(X + Y0 + Y1) * g + b ; Y0/Y1 are bf16 split-K partials.
// ---------------------------------------------------------------------------
__global__ __launch_bounds__(256)
void add_ln3_kernel(const float* __restrict__ X, const bf16_t* __restrict__ Y0,
                    const bf16_t* __restrict__ Y1,
                    const float* __restrict__ g, const float* __restrict__ be,
                    float* __restrict__ of, bf16_t* __restrict__ ob) {
    const int row = blockIdx.x, t = threadIdx.x;
    const float4 xv = ((const float4*)(X + (size_t)row * 1024))[t];
    const bf16x4_t y0 = ((const bf16x4_t*)(Y0 + (size_t)row * 1024))[t];
    const bf16x4_t y1 = ((const bf16x4_t*)(Y1 + (size_t)row * 1024))[t];
    float v[4] = {xv.x + (float)y0[0] + (float)y1[0], xv.y + (float)y0[1] + (float)y1[1],
                  xv.z + (float)y0[2] + (float)y1[2], xv.w + (float)y0[3] + (float)y1[3]};
    float s = v[0] + v[1] + v[2] + v[3];
    float s2 = v[0] * v[0] + v[1] * v[1] + v[2] * v[2] + v[3] * v[3];
#pragma unroll
    for (int m = 32; m >= 1; m >>= 1) { s += __shfl_xor(s, m); s2 += __shfl_xor(s2, m); }
    __shared__ float red[8];
    const int w = t >> 6, lane = t & 63;
    if (lane == 0) { red[w] = s; red[4 + w] = s2; }
    __syncthreads();
    s = red[0] + red[1] + red[2] + red[3];
    s2 = red[4] + red[5] + red[6] + red[7];
    const float mu = s * (1.f / 1024.f);
    const float var = s2 * (1.f / 1024.f) - mu * mu;
    const float rstd = rsqrtf(var + 1e-6f);
    const float4 gv = ((const float4*)g)[t];
    const float4 bv = ((const float4*)be)[t];
    float o[4];
    o[0] = (v[0] - mu) * rstd * gv.x + bv.x;
    o[1] = (v[1] - mu) * rstd * gv.y + bv.y;
    o[2] = (v[2] - mu) * rstd * gv.z + bv.z;
    o[3] = (v[3] - mu) * rstd * gv.w + bv.w;
    ((float4*)(of + (size_t)row * 1024))[t] = make_float4(o[0], o[1], o[2], o[3]);
    if (ob) {
        bf16x4_t qo;
        qo[0] = (bf16_t)o[0]; qo[1] = (bf16_t)o[1]; qo[2] = (bf16_t)o[2]; qo[3] = (bf16_t)o[3];
        ((bf16x4_t*)(ob + (size_t)row * 1024))[t] = qo;
    }
}

// ---------------------------------------------------------------------------
extern "C" void kernel_launch(void* const* d_in, const int* in_sizes, int n_in,
                              void* d_out, int out_size, void* d_ws, size_t ws_size,
                              hipStream_t stream) {
    (void)in_sizes; (void)n_in; (void)out_size; (void)ws_size;
    const float* q    = (const float*)d_in[0];
    const float* kv   = (const float*)d_in[1];
    const float* amap = (const float*)d_in[2];
    const float* Wq = (const float*)d_in[3];  const float* bQ = (const float*)d_in[4];
    const float* Wk = (const float*)d_in[5];  const float* bK = (const float*)d_in[6];
    const float* Wv = (const float*)d_in[7];  const float* bV = (const float*)d_in[8];
    const float* Wm = (const float*)d_in[9];  const float* bM = (const float*)d_in[10];
    const float* Wc1 = (const float*)d_in[11]; const float* bc1 = (const float*)d_in[12];
    const float* Wc2 = (const float*)d_in[13]; const float* bc2 = (const float*)d_in[14];
    const float* Wf1 = (const float*)d_in[15]; const float* bf1 = (const float*)d_in[16];
    const float* Wf2 = (const float*)d_in[17]; const float* bf2 = (const float*)d_in[18];
    const float* g1 = (const float*)d_in[19]; const float* b1 = (const float*)d_in[20];
    const float* g2 = (const float*)d_in[21]; const float* b2 = (const float*)d_in[22];

    char* w = (char*)d_ws;
    bf16_t* biasb = (bf16_t*)(w);                   // 64 MB, dead after attn
    bf16_t* p0    = (bf16_t*)(w);                   // 2x 8 MB partials (after attn)
    bf16_t* p1    = (bf16_t*)(w + 8388608);
    bf16_t* hb    = (bf16_t*)(w);                   // 32 MB (after add_ln3 #1)
    bf16_t* f0    = (bf16_t*)(w + 33554432);        // 2x 8 MB partials
    bf16_t* f1    = (bf16_t*)(w + 41943040);
    bf16_t* qb   = (bf16_t*)(w + 67108864);         // 8 MB ; ctx after QKV
    bf16_t* kvb  = (bf16_t*)(w + 75497472);         // 8 MB
    bf16_t* Qp   = (bf16_t*)(w + 83886080);         // 8 MB each, Q|K|V contiguous
    bf16_t* Kp   = (bf16_t*)(w + 92274688);
    bf16_t* Vp   = (bf16_t*)(w + 100663296);
    bf16_t* Wqkvb = (bf16_t*)(w + 109051904);       // 6 MB (Wq|Wk|Wv bf16)
    bf16_t* Wmb  = (bf16_t*)(w + 115343360);        // 2 MB
    bf16_t* Wf1b = (bf16_t*)(w + 117440512);        // 8 MB
    bf16_t* Wf2b = (bf16_t*)(w + 125829120);        // 8 MB
    float*  bqkv = (float*)(w + 134217728);         // 12 KB
    bf16_t* logmap = (bf16_t*)(w + 167772160);      // 67 MB (position-major log2 map)
    bf16_t* ctx = qb;                               // qb dead after QKV gemm
    float*  xf  = (float*)Qp;                       // 16 MB over Qp+Kp
    bf16_t* xb  = Vp;                               // Vp dead after attn

    dim3 blk(256);
    cvt_all_kernel<<<20480, blk, 0, stream>>>(q, kv, Wq, Wk, Wv, Wm, Wf1, Wf2,
                                              qb, Wqkvb, Wf1b);
    pack3_kernel<<<4, blk, 0, stream>>>(bQ, bK, bV, bqkv);

    // streaming log2 pre-pass, then MFMA bias-MLP on the compact map
    logmap_kernel<<<8192, blk, 0, stream>>>(amap, logmap);
    bias_mlp_mfma<<<8192, blk, 0, stream>>>(logmap, Wc1, bc1, Wc2, bc2, biasb);

    // fused QKV projection: 256^2 8-phase, N=3072 (192 blocks)
    gemm8p<3><<<192, dim3(512), 0, stream>>>(qb, kvb, Wqkvb, bqkv, Qp,
                                             4096, 3072, 1024, 1024);

    attn_kernel<<<1024, blk, 0, stream>>>(Qp, Kp, Vp, biasb, ctx);

    // out-proj, split-K=2 -> bf16 partials p0,p1 (biasb region, dead now)
    gemm_bt<0, true><<<dim3(256, 2), blk, 0, stream>>>(ctx, nullptr, Wmb, bM, p0,
                                                       4096, 1024, 512, 1024);
    add_ln3_kernel<<<4096, blk, 0, stream>>>(q, p0, p1, g1, b1, xf, xb);

    // FFN1 (relu, bf16): 256^2 8-phase, N=4096 (256 blocks)
    gemm8p<2><<<256, dim3(512), 0, stream>>>(xb, nullptr, Wf1b, bf1, hb,
                                             4096, 4096, 1024, 1024);
    // FFN2, split-K=2 -> bf16 partials f0,f1
    gemm_bt<0, true><<<dim3(256, 2), blk, 0, stream>>>(hb, nullptr, Wf2b, bf2, f0,
                                                       4096, 1024, 2048, 4096);
    add_ln3_kernel<<<4096, blk, 0, stream>>>(xf, f0, f1, g2, b2, (float*)d_out, nullptr);
}

// Round 13
// 319.588 us; speedup vs baseline: 1.1056x; 1.1056x over previous
//
#include <hip/hip_runtime.h>
#include <hip/hip_bf16.h>

typedef __bf16 bf16_t;
typedef __bf16 bf16x4_t __attribute__((ext_vector_type(4)));
typedef __bf16 bf16x8_t __attribute__((ext_vector_type(8)));
typedef float  f32x4_t  __attribute__((ext_vector_type(4)));

#define B_   8
#define LQ_  512
#define LKV_ 512
#define D_   1024
#define H_   16
#define DH_  64
#define FF_  4096

__device__ __forceinline__ f32x4_t mfma16(bf16x8_t a, bf16x8_t b, f32x4_t c) {
    return __builtin_amdgcn_mfma_f32_16x16x32_bf16(a, b, c, 0, 0, 0);
}

__device__ __forceinline__ void gload_lds16(const bf16_t* g, bf16_t* l) {
    __builtin_amdgcn_global_load_lds(
        (const __attribute__((address_space(1))) void*)g,
        (__attribute__((address_space(3))) void*)l, 16, 0, 0);
}

// bijective XCD chunking (requires nwg % 8 == 0)
__device__ __forceinline__ int xcd_swz(int pid, int nwg) {
    return (pid & 7) * (nwg >> 3) + (pid >> 3);
}

// fast GELU: h * sigmoid(1.702 h).
__device__ __forceinline__ float gelu_fast(float h) {
    const float e = exp2f(h * -2.45546696f);     // exp(-1.702 h)
    return h * __builtin_amdgcn_rcpf(1.f + e);
}

// ---------------------------------------------------------------------------
// fused f32 -> bf16 convert for all 8 tensors (one launch).
// ---------------------------------------------------------------------------
__global__ __launch_bounds__(256)
void cvt_all_kernel(const float* __restrict__ q,  const float* __restrict__ kv,
                    const float* __restrict__ Wq, const float* __restrict__ Wk,
                    const float* __restrict__ Wv, const float* __restrict__ Wm,
                    const float* __restrict__ Wf1,const float* __restrict__ Wf2,
                    bf16_t* __restrict__ dq, bf16_t* __restrict__ dW,
                    bf16_t* __restrict__ dF) {
    const int i = blockIdx.x * 256 + threadIdx.x;    // grid 20480 -> i < 5242880
    const float* s; bf16_t* d; int j;
    if (i < 1048576)      { s = q;   d = dq;           j = i; }
    else if (i < 2097152) { s = kv;  d = dq + 4194304; j = i - 1048576; }
    else if (i < 2359296) { s = Wq;  d = dW;           j = i - 2097152; }
    else if (i < 2621440) { s = Wk;  d = dW + 1048576; j = i - 2359296; }
    else if (i < 2883584) { s = Wv;  d = dW + 2097152; j = i - 2621440; }
    else if (i < 3145728) { s = Wm;  d = dW + 3145728; j = i - 2883584; }
    else if (i < 4194304) { s = Wf1; d = dF;           j = i - 3145728; }
    else                  { s = Wf2; d = dF + 4194304; j = i - 4194304; }
    const float4 v = ((const float4*)s)[j];
    bf16x4_t o;
    o[0] = (bf16_t)v.x; o[1] = (bf16_t)v.y; o[2] = (bf16_t)v.z; o[3] = (bf16_t)v.w;
    ((bf16x4_t*)d)[j] = o;
}

__global__ __launch_bounds__(256)
void pack3_kernel(const float* __restrict__ a, const float* __restrict__ b,
                  const float* __restrict__ c, float* __restrict__ o) {
    const int i = blockIdx.x * 256 + threadIdx.x;   // grid 4 -> i < 1024
    o[i] = a[i]; o[1024 + i] = b[i]; o[2048 + i] = c[i];
}

// ---------------------------------------------------------------------------
// AttentionBiasMLP via MFMA (r9/323us version: inline log2, 32KB LDS).
// Transcendental-bound (~16 log + 32 exp + 32 rcp per lane) -- near floor.
// ---------------------------------------------------------------------------
__global__ __launch_bounds__(256)
void bias_mlp_mfma(const float* __restrict__ amap,
                   const float* __restrict__ Wc1, const float* __restrict__ bc1,
                   const float* __restrict__ Wc2, const float* __restrict__ bc2,
                   bf16_t* __restrict__ biasb) {
    __shared__ __align__(16) char lds[4][8192];
    const int t = threadIdx.x, lane = t & 63, w = t >> 6;
    const int l15 = lane & 15, lg = lane >> 4;
    char* Xs = lds[w];
    char* Hs = lds[w] + 3072;

    bf16x8_t b1f[2], b2f;
    f32x4_t bc1v[2];
#pragma unroll
    for (int ot = 0; ot < 2; ot++) {
        bf16x8_t v;
#pragma unroll
        for (int i = 0; i < 8; i++) {
            const int kk = (lg * 8 + i) & 15;
            const float wv = Wc1[(ot * 16 + l15) * 16 + kk] * 0.69314718055994531f;
            v[i] = (lg < 2) ? (bf16_t)wv : (bf16_t)0.f;
        }
        b1f[ot] = v;
        const float bb = bc1[ot * 16 + l15];
        bc1v[ot] = f32x4_t{bb, bb, bb, bb};
    }
    {
        bf16x8_t v;
#pragma unroll
        for (int i = 0; i < 8; i++) v[i] = (bf16_t)Wc2[l15 * 32 + lg * 8 + i];
        b2f = v;
    }
    const float bc2s = bc2[l15];
    const f32x4_t cinit2 = f32x4_t{bc2s, bc2s, bc2s, bc2s};

    const int posb = (blockIdx.x * 4 + w) * 64;
    const int b  = posb >> 18;
    const int q  = (posb >> 9) & 511;
    const int k0 = posb & 511;

    const float* src = amap + (size_t)(b * 16) * 263169 + (size_t)(q + 1) * 513 + (k0 + 1 + lane);
    bf16_t xr[16];
#pragma unroll
    for (int c = 0; c < 16; c++) {
        const float v = src[(size_t)c * 263169];
        xr[c] = (bf16_t)__log2f(v + 1e-6f);
    }
    *(bf16x8_t*)(Xs + lane * 48)      = *(bf16x8_t*)&xr[0];
    *(bf16x8_t*)(Xs + lane * 48 + 16) = *(bf16x8_t*)&xr[8];

    const int lgm16 = (lg & 1) * 16;
    f32x4_t h1[4][2];
#pragma unroll
    for (int p = 0; p < 4; p++) {
        const bf16x8_t a1 = *(const bf16x8_t*)(Xs + (p * 16 + l15) * 48 + lgm16);
#pragma unroll
        for (int ot = 0; ot < 2; ot++)
            h1[p][ot] = mfma16(a1, b1f[ot], bc1v[ot]);
    }

#pragma unroll
    for (int p = 0; p < 4; p++)
#pragma unroll
        for (int ot = 0; ot < 2; ot++)
#pragma unroll
            for (int r = 0; r < 4; r++) {
                const float g = gelu_fast(h1[p][ot][r]);
                *(bf16_t*)(Hs + (p * 16 + lg * 4 + r) * 80 + (ot * 16 + l15) * 2) = (bf16_t)g;
            }

    const size_t obase = ((size_t)(b * 16 + l15) * 512 + q) * 512 + k0;
#pragma unroll
    for (int p = 0; p < 4; p++) {
        const bf16x8_t a2 = *(const bf16x8_t*)(Hs + (p * 16 + l15) * 80 + lg * 16);
        const f32x4_t o2 = mfma16(a2, b2f, cinit2);
        bf16x4_t ov;
#pragma unroll
        for (int r = 0; r < 4; r++) ov[r] = (bf16_t)o2[r];
        *(bf16x4_t*)&biasb[obase + p * 16 + lg * 4] = ov;
    }
}

// ---------------------------------------------------------------------------
// 128^2 bf16 GEMM (3-slot pipeline) -- out-proj (N=1024).
// LDS chunk-swizzle s(r)=r&3 both-sides.
// ---------------------------------------------------------------------------
template <int EPI, bool SPLIT>
__global__ __launch_bounds__(256)
void gemm_bt(const bf16_t* __restrict__ A, const bf16_t* __restrict__ A2,
             const bf16_t* __restrict__ Bw,
             const float* __restrict__ bias,
             bf16_t* __restrict__ Cb, int M, int N, int Klen, int lda) {
    __shared__ __align__(16) bf16_t As[3][128 * 32];
    __shared__ __align__(16) bf16_t Bs[3][128 * 32];
    const int t = threadIdx.x, lane = t & 63, w = t >> 6;
    const int wr = w >> 1, wc = w & 1;
    const int ntn = N >> 7;
    const int nwg = (M >> 7) * ntn;
    const int wg  = xcd_swz((int)blockIdx.x, nwg);
    const int gsz = 8 * ntn;
    const int gid = wg / gsz;
    const int rem = wg - gid * gsz;
    const int tm  = gid * 8 + (rem & 7);
    const int tn  = rem >> 3;
    const int l15 = lane & 15, lg = lane >> 4;
    const int ks = SPLIT ? blockIdx.y : 0;
    const int koff = SPLIT ? ks * Klen : 0;

    const int r0 = t >> 2,          sk0 = (t & 3) ^ ((t >> 2) & 3);
    const int r1 = (t + 256) >> 2,  sk1 = (t & 3) ^ ((t >> 2) & 3);
    const int b0 = (w * 64) * 8;
    const int b1 = (256 + w * 64) * 8;
    const bf16_t* Abase0 = A  + (size_t)(tm * 128 + r0) * lda + koff + sk0 * 8;
    const bf16_t* Abase1 = A  + (size_t)(tm * 128 + r1) * lda + koff + sk1 * 8;
    const bf16_t* Bbase0 = Bw + (size_t)(tn * 128 + r0) * lda + koff + sk0 * 8;
    const bf16_t* Bbase1 = Bw + (size_t)(tn * 128 + r1) * lda + koff + sk1 * 8;

    f32x4_t acc[4][4];
#pragma unroll
    for (int i = 0; i < 4; i++)
#pragma unroll
        for (int j = 0; j < 4; j++) acc[i][j] = f32x4_t{0.f, 0.f, 0.f, 0.f};

    const int nk = Klen >> 5;

#define STAGE128(KT, S)                                 \
    do {                                                \
        const int _ko = (KT) * 32;                      \
        gload_lds16(Abase0 + _ko, &As[(S)][b0]);        \
        gload_lds16(Abase1 + _ko, &As[(S)][b1]);        \
        gload_lds16(Bbase0 + _ko, &Bs[(S)][b0]);        \
        gload_lds16(Bbase1 + _ko, &Bs[(S)][b1]);        \
    } while (0)

    STAGE128(0, 0);
    STAGE128(1, 1);

    const int rsw = l15 & 3;           // read-side row&3
    int cur = 0;
    for (int kt = 0; kt < nk; ++kt) {
        if (kt + 1 < nk) { asm volatile("s_waitcnt vmcnt(4)" ::: "memory"); }
        else             { asm volatile("s_waitcnt vmcnt(0)" ::: "memory"); }
        __syncthreads();
        if (kt + 2 < nk) {
            const int s2 = cur >= 1 ? cur - 1 : cur + 2;
            STAGE128(kt + 2, s2);
        }

        const bf16_t* Ac = As[cur];
        const bf16_t* Bc = Bs[cur];
        bf16x8_t af[4], bfv[4];
#pragma unroll
        for (int mt = 0; mt < 4; mt++)
            af[mt] = *(const bf16x8_t*)&Ac[(wr * 64 + mt * 16 + l15) * 32 + ((lg ^ rsw) * 8)];
#pragma unroll
        for (int nt = 0; nt < 4; nt++)
            bfv[nt] = *(const bf16x8_t*)&Bc[(wc * 64 + nt * 16 + l15) * 32 + ((lg ^ rsw) * 8)];
#pragma unroll
        for (int mt = 0; mt < 4; mt++)
#pragma unroll
            for (int nt = 0; nt < 4; nt++)
                acc[mt][nt] = mfma16(af[mt], bfv[nt], acc[mt][nt]);

        cur = cur < 2 ? cur + 1 : 0;
    }
#undef STAGE128

#pragma unroll
    for (int nt = 0; nt < 4; nt++) {
        const int col = tn * 128 + wc * 64 + nt * 16 + l15;
        float bv = bias[col];
        if (SPLIT && ks != 0) bv = 0.f;
#pragma unroll
        for (int mt = 0; mt < 4; mt++) {
#pragma unroll
            for (int r = 0; r < 4; r++) {
                const int row = tm * 128 + wr * 64 + mt * 16 + lg * 4 + r;
                float v = acc[mt][nt][r] + bv;
                if (EPI == 2) v = fmaxf(v, 0.f);
                if (SPLIT)
                    Cb[(size_t)ks * M * N + (size_t)row * N + col] = (bf16_t)v;
                else Cb[(size_t)row * N + col] = (bf16_t)v;
            }
        }
    }
}

// ---------------------------------------------------------------------------
// 256^2 BK=64 8-wave phase-split GEMM.  LDS chunk-swizzle s(r)=r&7 both-sides.
// EPI: 0 = plain bf16 (split partial), 2 = relu bf16 (FFN1), 3 = QKV fused.
// SPLIT: blockIdx.y = K-slice; partials at Cb + ks*M*N; bias on ks==0 only.
// ---------------------------------------------------------------------------
template <int EPI, bool SPLIT>
__global__ __launch_bounds__(512, 1)
void gemm8p(const bf16_t* __restrict__ A, const bf16_t* __restrict__ A2,
            const bf16_t* __restrict__ Bw, const float* __restrict__ bias,
            bf16_t* __restrict__ Cb, int M, int N, int Klen, int lda) {
    __shared__ __align__(16) bf16_t As[2][256 * 64];   // 32 KB per buffer
    __shared__ __align__(16) bf16_t Bs[2][256 * 64];   // total LDS 128 KB
    const int t = threadIdx.x, lane = t & 63, w = t >> 6;     // 8 waves
    const int wr = w >> 2, wc = w & 3;                        // 2 x 4 wave grid
    const int l15 = lane & 15, lg = lane >> 4;
    const int ntn = N >> 8;
    const int nwg = (M >> 8) * ntn;
    const int wg  = xcd_swz((int)blockIdx.x, nwg);
    const int gsz = 8 * ntn;
    const int gid = wg / gsz;
    const int rem = wg - gid * gsz;
    const int tm  = gid * 8 + (rem & 7);
    const int tn  = rem >> 3;
    const int ks   = SPLIT ? blockIdx.y : 0;
    const int koff = SPLIT ? ks * Klen : 0;
    if (EPI == 3 && tn >= 4) A = A2;    // cols >= 1024 use kv input

    const int srow = w * 8 + (lane >> 3);
    const int scol = ((lane & 7) ^ (lane >> 3)) * 8;
    const bf16_t* Ag = A  + (size_t)(tm * 256 + srow) * lda + koff + scol;
    const bf16_t* Bg = Bw + (size_t)(tn * 256 + srow) * lda + koff + scol;
    const int ldsb = w * 512;

#define STAGE256(KT, S)                                                      \
    do {                                                                     \
        const size_t _ko = (size_t)(KT) * 64;                                \
        _Pragma("unroll")                                                    \
        for (int _i = 0; _i < 4; _i++) {                                     \
            gload_lds16(Ag + (size_t)(_i * 64) * lda + _ko,                  \
                        &As[(S)][_i * 4096 + ldsb]);                         \
            gload_lds16(Bg + (size_t)(_i * 64) * lda + _ko,                  \
                        &Bs[(S)][_i * 4096 + ldsb]);                         \
        }                                                                    \
    } while (0)

    f32x4_t acc[8][4];
#pragma unroll
    for (int i = 0; i < 8; i++)
#pragma unroll
        for (int j = 0; j < 4; j++) acc[i][j] = f32x4_t{0.f, 0.f, 0.f, 0.f};

    const int nk = Klen >> 6;          // K=1024 -> 16

    STAGE256(0, 0);
    STAGE256(1, 1);

    const int rsw = l15 & 7;           // read-side row&7
    for (int kt = 0; kt < nk; ++kt) {
        const int s = kt & 1;
        if (kt + 1 < nk) { asm volatile("s_waitcnt vmcnt(8)" ::: "memory"); }
        else             { asm volatile("s_waitcnt vmcnt(0)" ::: "memory"); }
        __builtin_amdgcn_s_barrier();            // barrier A: tile kt visible
        __builtin_amdgcn_sched_barrier(0);

#pragma unroll
        for (int q = 0; q < 4; q++) {            // quadrant (mh, nh)
            const int mh = q >> 1, nh = q & 1;
            bf16x8_t af[4][2], bfv[2][2];
#pragma unroll
            for (int mi = 0; mi < 4; mi++) {
                const int row = wr * 128 + (mh * 4 + mi) * 16 + l15;
#pragma unroll
                for (int kk = 0; kk < 2; kk++)
                    af[mi][kk] = *(const bf16x8_t*)&As[s][row * 64 + (((kk * 4 + lg) ^ rsw) * 8)];
            }
#pragma unroll
            for (int ni = 0; ni < 2; ni++) {
                const int row = wc * 64 + (nh * 2 + ni) * 16 + l15;
#pragma unroll
                for (int kk = 0; kk < 2; kk++)
                    bfv[ni][kk] = *(const bf16x8_t*)&Bs[s][row * 64 + (((kk * 4 + lg) ^ rsw) * 8)];
            }
            __builtin_amdgcn_s_setprio(1);
#pragma unroll
            for (int mi = 0; mi < 4; mi++)
#pragma unroll
                for (int ni = 0; ni < 2; ni++)
#pragma unroll
                    for (int kk = 0; kk < 2; kk++)
                        acc[mh * 4 + mi][nh * 2 + ni] =
                            mfma16(af[mi][kk], bfv[ni][kk], acc[mh * 4 + mi][nh * 2 + ni]);
            __builtin_amdgcn_s_setprio(0);
        }

        __builtin_amdgcn_sched_barrier(0);
        __builtin_amdgcn_s_barrier();            // barrier B: all reads retired
        __builtin_amdgcn_sched_barrier(0);
        if (kt + 2 < nk) STAGE256(kt + 2, s);    // refill freed buffer
    }
#undef STAGE256

    // epilogue
#pragma unroll
    for (int n = 0; n < 4; n++) {
        const int col = tn * 256 + wc * 64 + n * 16 + l15;
        float bv = bias[col];
        if (SPLIT && ks != 0) bv = 0.f;
#pragma unroll
        for (int m = 0; m < 8; m++) {
#pragma unroll
            for (int r = 0; r < 4; r++) {
                const int row = tm * 256 + wr * 128 + m * 16 + lg * 4 + r;
                float v = acc[m][n][r] + bv;
                if (EPI == 2) v = fmaxf(v, 0.f);
                if (EPI == 3 && tn < 4) v *= 0.125f;
                if (SPLIT)
                    Cb[(size_t)ks * M * N + (size_t)row * N + col] = (bf16_t)v;
                else if (EPI == 3)
                    Cb[(size_t)(col >> 10) * 4194304 + (size_t)row * 1024 + (col & 1023)] = (bf16_t)v;
                else
                    Cb[(size_t)row * N + col] = (bf16_t)v;
            }
        }
    }
}

// ---------------------------------------------------------------------------
// Flash attention with additive bias (unchanged from the 323us config).
// ---------------------------------------------------------------------------
__global__ __launch_bounds__(256)
void attn_kernel(const bf16_t* __restrict__ Qp, const bf16_t* __restrict__ Kp,
                 const bf16_t* __restrict__ Vp, const bf16_t* __restrict__ biasb,
                 bf16_t* __restrict__ ctx) {
    __shared__ __align__(16) bf16_t Qs[64 * 64];
    __shared__ __align__(16) bf16_t Ks[64 * 64];
    __shared__ __align__(16) bf16_t Vts[64 * 64];
    __shared__ __align__(16) bf16_t Ps[64 * 64];
    __shared__ __align__(16) bf16_t Bbs[64 * 64];

    const int bid = xcd_swz((int)blockIdx.x, 1024);
    const int qt = bid & 7, h = (bid >> 3) & 15, b = bid >> 7;
    const int t = threadIdx.x, lane = t & 63, w = t >> 6;
    const int l15 = lane & 15, lg = lane >> 4;

#pragma unroll
    for (int i = 0; i < 2; i++) {
        const int c = t + i * 256;
        const int row = c >> 3, cg = c & 7;
        const uint4 v = *(const uint4*)&Qp[(((size_t)(b * LQ_ + qt * 64 + row)) * H_ + h) * DH_ + cg * 8];
        *(uint4*)((char*)Qs + row * 128 + ((cg ^ (row & 7)) << 4)) = v;
    }
    __syncthreads();

    bf16x8_t aq[2];
    {
        const int rowq = w * 16 + l15;
#pragma unroll
        for (int kc = 0; kc < 2; kc++)
            aq[kc] = *(const bf16x8_t*)((const char*)Qs + rowq * 128 + (((kc * 4 + lg) ^ (rowq & 7)) << 4));
    }

    f32x4_t oacc[4];
#pragma unroll
    for (int i = 0; i < 4; i++) oacc[i] = f32x4_t{0.f, 0.f, 0.f, 0.f};
    float mrow[4] = {-1e30f, -1e30f, -1e30f, -1e30f};
    float lrow[4] = {0.f, 0.f, 0.f, 0.f};

    const bf16_t* bias_tile = biasb + ((size_t)(b * H_ + h) * LQ_ + qt * 64) * LKV_;

    for (int kt = 0; kt < 8; ++kt) {
        __syncthreads();
#pragma unroll
        for (int i = 0; i < 2; i++) {
            const int c = t + i * 256;
            const int row = c >> 3, cg = c & 7;
            const uint4 v = *(const uint4*)&Kp[(((size_t)(b * LKV_ + kt * 64 + row)) * H_ + h) * DH_ + cg * 8];
            *(uint4*)((char*)Ks + row * 128 + ((cg ^ (row & 7)) << 4)) = v;
        }
#pragma unroll
        for (int i = 0; i < 2; i++) {
            const int c = t + i * 256;
            const int row = c >> 3, cg = c & 7;
            const uint4 bv4 = *(const uint4*)&bias_tile[(size_t)row * LKV_ + kt * 64 + cg * 8];
            *(uint4*)&Bbs[row * 64 + cg * 8] = bv4;
        }
#pragma unroll
        for (int i = 0; i < 2; i++) {
            const int c = t + i * 256;
            const int k = c >> 3, dg = c & 7;
            const bf16x8_t vv = *(const bf16x8_t*)&Vp[(((size_t)(b * LKV_ + kt * 64 + k)) * H_ + h) * DH_ + dg * 8];
#pragma unroll
            for (int j = 0; j < 8; j++) {
                const int d = dg * 8 + j;
                *(bf16_t*)((char*)Vts + d * 128 + ((((k * 2) >> 4) ^ (d & 7)) << 4) + ((k * 2) & 15)) = vv[j];
            }
        }
        __syncthreads();

        f32x4_t sacc[4];
#pragma unroll
        for (int i = 0; i < 4; i++) sacc[i] = f32x4_t{0.f, 0.f, 0.f, 0.f};
#pragma unroll
        for (int nt = 0; nt < 4; nt++) {
            const int rowk = nt * 16 + l15;
#pragma unroll
            for (int kc = 0; kc < 2; kc++) {
                const bf16x8_t bk = *(const bf16x8_t*)((const char*)Ks + rowk * 128 + (((kc * 4 + lg) ^ (rowk & 7)) << 4));
                sacc[nt] = mfma16(aq[kc], bk, sacc[nt]);
            }
        }

        float esc[4];
#pragma unroll
        for (int r = 0; r < 4; r++) {
            const int qr = w * 16 + lg * 4 + r;
            float mx = -1e30f;
#pragma unroll
            for (int nt = 0; nt < 4; nt++) {
                const float bvv = (float)Bbs[qr * 64 + nt * 16 + l15];
                const float v = sacc[nt][r] + bvv;
                sacc[nt][r] = v;
                mx = fmaxf(mx, v);
            }
#pragma unroll
            for (int msk = 8; msk >= 1; msk >>= 1) mx = fmaxf(mx, __shfl_xor(mx, msk));
            const float mnew = fmaxf(mrow[r], mx);
            esc[r] = __expf(mrow[r] - mnew);
            mrow[r] = mnew;
            float rs = 0.f;
#pragma unroll
            for (int nt = 0; nt < 4; nt++) {
                const float p = __expf(sacc[nt][r] - mnew);
                sacc[nt][r] = p;
                rs += p;
            }
#pragma unroll
            for (int msk = 8; msk >= 1; msk >>= 1) rs += __shfl_xor(rs, msk);
            lrow[r] = lrow[r] * esc[r] + rs;
        }

#pragma unroll
        for (int r = 0; r < 4; r++) {
            const int prow = w * 16 + lg * 4 + r;
#pragma unroll
            for (int nt = 0; nt < 4; nt++) {
                const int pc2 = (nt * 16 + l15) * 2;
                *(bf16_t*)((char*)Ps + prow * 128 + (((pc2 >> 4) ^ (prow & 7)) << 4) + (pc2 & 15)) =
                    (bf16_t)sacc[nt][r];
            }
        }
        asm volatile("s_waitcnt lgkmcnt(0)" ::: "memory");
        __builtin_amdgcn_sched_barrier(0);

#pragma unroll
        for (int dt = 0; dt < 4; dt++)
#pragma unroll
            for (int r = 0; r < 4; r++) oacc[dt][r] *= esc[r];

        bf16x8_t pa[2];
        {
            const int rowp = w * 16 + l15;
#pragma unroll
            for (int kc = 0; kc < 2; kc++)
                pa[kc] = *(const bf16x8_t*)((const char*)Ps + rowp * 128 + (((kc * 4 + lg) ^ (rowp & 7)) << 4));
        }
#pragma unroll
        for (int dt = 0; dt < 4; dt++) {
            const int rowv = dt * 16 + l15;
#pragma unroll
            for (int kc = 0; kc < 2; kc++) {
                const bf16x8_t bv = *(const bf16x8_t*)((const char*)Vts + rowv * 128 + (((kc * 4 + lg) ^ (rowv & 7)) << 4));
                oacc[dt] = mfma16(pa[kc], bv, oacc[dt]);
            }
        }
    }

    float inv[4];
#pragma unroll
    for (int r = 0; r < 4; r++) inv[r] = __builtin_amdgcn_rcpf(lrow[r]);
#pragma unroll
    for (int dt = 0; dt < 4; dt++) {
#pragma unroll
        for (int r = 0; r < 4; r++) {
            const float v = oacc[dt][r] * inv[r];
            const int q = qt * 64 + w * 16 + lg * 4 + r;
            const int d = dt * 16 + l15;
            ctx[(((size_t)(b * LQ_ + q)) * H_ + h) * DH_ + d] = (bf16_t)v;
        }
    }
}

// ---------------------------------------------------------------------------
// out = LayerNorm(X + Y0 + Y1) * g + b ; Y0/Y1 are bf16 split-K partials.
// ---------------------------------------------------------------------------
__global__ __launch_bounds__(256)
void add_ln3_kernel(const float* __restrict__ X, const bf16_t* __restrict__ Y0,
                    const bf16_t* __restrict__ Y1,
                    const float* __restrict__ g, const float* __restrict__ be,
                    float* __restrict__ of, bf16_t* __restrict__ ob) {
    const int row = blockIdx.x, t = threadIdx.x;
    const float4 xv = ((const float4*)(X + (size_t)row * 1024))[t];
    const bf16x4_t y0 = ((const bf16x4_t*)(Y0 + (size_t)row * 1024))[t];
    const bf16x4_t y1 = ((const bf16x4_t*)(Y1 + (size_t)row * 1024))[t];
    float v[4] = {xv.x + (float)y0[0] + (float)y1[0], xv.y + (float)y0[1] + (float)y1[1],
                  xv.z + (float)y0[2] + (float)y1[2], xv.w + (float)y0[3] + (float)y1[3]};
    float s = v[0] + v[1] + v[2] + v[3];
    float s2 = v[0] * v[0] + v[1] * v[1] + v[2] * v[2] + v[3] * v[3];
#pragma unroll
    for (int m = 32; m >= 1; m >>= 1) { s += __shfl_xor(s, m); s2 += __shfl_xor(s2, m); }
    __shared__ float red[8];
    const int w = t >> 6, lane = t & 63;
    if (lane == 0) { red[w] = s; red[4 + w] = s2; }
    __syncthreads();
    s = red[0] + red[1] + red[2] + red[3];
    s2 = red[4] + red[5] + red[6] + red[7];
    const float mu = s * (1.f / 1024.f);
    const float var = s2 * (1.f / 1024.f) - mu * mu;
    const float rstd = rsqrtf(var + 1e-6f);
    const float4 gv = ((const float4*)g)[t];
    const float4 bv = ((const float4*)be)[t];
    float o[4];
    o[0] = (v[0] - mu) * rstd * gv.x + bv.x;
    o[1] = (v[1] - mu) * rstd * gv.y + bv.y;
    o[2] = (v[2] - mu) * rstd * gv.z + bv.z;
    o[3] = (v[3] - mu) * rstd * gv.w + bv.w;
    ((float4*)(of + (size_t)row * 1024))[t] = make_float4(o[0], o[1], o[2], o[3]);
    if (ob) {
        bf16x4_t qo;
        qo[0] = (bf16_t)o[0]; qo[1] = (bf16_t)o[1]; qo[2] = (bf16_t)o[2]; qo[3] = (bf16_t)o[3];
        ((bf16x4_t*)(ob + (size_t)row * 1024))[t] = qo;
    }
}

// ---------------------------------------------------------------------------
// out = LayerNorm(X + Y0+Y1+Y2+Y3) * g + b ; Yi are bf16 split-K partials.
// ---------------------------------------------------------------------------
__global__ __launch_bounds__(256)
void add_ln5_kernel(const float* __restrict__ X, const bf16_t* __restrict__ Y0,
                    const bf16_t* __restrict__ Y1, const bf16_t* __restrict__ Y2,
                    const bf16_t* __restrict__ Y3,
                    const float* __restrict__ g, const float* __restrict__ be,
                    float* __restrict__ of, bf16_t* __restrict__ ob) {
    const int row = blockIdx.x, t = threadIdx.x;
    const float4 xv = ((const float4*)(X + (size_t)row * 1024))[t];
    const bf16x4_t y0 = ((const bf16x4_t*)(Y0 + (size_t)row * 1024))[t];
    const bf16x4_t y1 = ((const bf16x4_t*)(Y1 + (size_t)row * 1024))[t];
    const bf16x4_t y2 = ((const bf16x4_t*)(Y2 + (size_t)row * 1024))[t];
    const bf16x4_t y3 = ((const bf16x4_t*)(Y3 + (size_t)row * 1024))[t];
    float v[4];
    v[0] = xv.x + ((float)y0[0] + (float)y1[0]) + ((float)y2[0] + (float)y3[0]);
    v[1] = xv.y + ((float)y0[1] + (float)y1[1]) + ((float)y2[1] + (float)y3[1]);
    v[2] = xv.z + ((float)y0[2] + (float)y1[2]) + ((float)y2[2] + (float)y3[2]);
    v[3] = xv.w + ((float)y0[3] + (float)y1[3]) + ((float)y2[3] + (float)y3[3]);
    float s = v[0] + v[1] + v[2] + v[3];
    float s2 = v[0] * v[0] + v[1] * v[1] + v[2] * v[2] + v[3] * v[3];
#pragma unroll
    for (int m = 32; m >= 1; m >>= 1) { s += __shfl_xor(s, m); s2 += __shfl_xor(s2, m); }
    __shared__ float red[8];
    const int w = t >> 6, lane = t & 63;
    if (lane == 0) { red[w] = s; red[4 + w] = s2; }
    __syncthreads();
    s = red[0] + red[1] + red[2] + red[3];
    s2 = red[4] + red[5] + red[6] + red[7];
    const float mu = s * (1.f / 1024.f);
    const float var = s2 * (1.f / 1024.f) - mu * mu;
    const float rstd = rsqrtf(var + 1e-6f);
    const float4 gv = ((const float4*)g)[t];
    const float4 bv = ((const float4*)be)[t];
    float o[4];
    o[0] = (v[0] - mu) * rstd * gv.x + bv.x;
    o[1] = (v[1] - mu) * rstd * gv.y + bv.y;
    o[2] = (v[2] - mu) * rstd * gv.z + bv.z;
    o[3] = (v[3] - mu) * rstd * gv.w + bv.w;
    ((float4*)(of + (size_t)row * 1024))[t] = make_float4(o[0], o[1], o[2], o[3]);
    if (ob) {
        bf16x4_t qo;
        qo[0] = (bf16_t)o[0]; qo[1] = (bf16_t)o[1]; qo[2] = (bf16_t)o[2]; qo[3] = (bf16_t)o[3];
        ((bf16x4_t*)(ob + (size_t)row * 1024))[t] = qo;
    }
}

// ---------------------------------------------------------------------------
extern "C" void kernel_launch(void* const* d_in, const int* in_sizes, int n_in,
                              void* d_out, int out_size, void* d_ws, size_t ws_size,
                              hipStream_t stream) {
    (void)in_sizes; (void)n_in; (void)out_size; (void)ws_size;
    const float* q    = (const float*)d_in[0];
    const float* kv   = (const float*)d_in[1];
    const float* amap = (const float*)d_in[2];
    const float* Wq = (const float*)d_in[3];  const float* bQ = (const float*)d_in[4];
    const float* Wk = (const float*)d_in[5];  const float* bK = (const float*)d_in[6];
    const float* Wv = (const float*)d_in[7];  const float* bV = (const float*)d_in[8];
    const float* Wm = (const float*)d_in[9];  const float* bM = (const float*)d_in[10];
    const float* Wc1 = (const float*)d_in[11]; const float* bc1 = (const float*)d_in[12];
    const float* Wc2 = (const float*)d_in[13]; const float* bc2 = (const float*)d_in[14];
    const float* Wf1 = (const float*)d_in[15]; const float* bf1 = (const float*)d_in[16];
    const float* Wf2 = (const float*)d_in[17]; const float* bf2 = (const float*)d_in[18];
    const float* g1 = (const float*)d_in[19]; const float* b1 = (const float*)d_in[20];
    const float* g2 = (const float*)d_in[21]; const float* b2 = (const float*)d_in[22];

    char* w = (char*)d_ws;
    bf16_t* biasb = (bf16_t*)(w);                   // 64 MB, dead after attn
    bf16_t* p0    = (bf16_t*)(w);                   // 2x 8 MB partials (after attn)
    bf16_t* p1    = (bf16_t*)(w + 8388608);
    bf16_t* hb    = (bf16_t*)(w);                   // 32 MB (after add_ln3 #1)
    bf16_t* f0    = (bf16_t*)(w + 33554432);        // 4x 8 MB partials [33.5,67) MB
    bf16_t* qb   = (bf16_t*)(w + 67108864);         // 8 MB ; ctx after QKV
    bf16_t* kvb  = (bf16_t*)(w + 75497472);         // 8 MB
    bf16_t* Qp   = (bf16_t*)(w + 83886080);         // 8 MB each, Q|K|V contiguous
    bf16_t* Kp   = (bf16_t*)(w + 92274688);
    bf16_t* Vp   = (bf16_t*)(w + 100663296);
    bf16_t* Wqkvb = (bf16_t*)(w + 109051904);       // 6 MB (Wq|Wk|Wv bf16)
    bf16_t* Wmb  = (bf16_t*)(w + 115343360);        // 2 MB
    bf16_t* Wf1b = (bf16_t*)(w + 117440512);        // 8 MB
    bf16_t* Wf2b = (bf16_t*)(w + 125829120);        // 8 MB
    float*  bqkv = (float*)(w + 134217728);         // 12 KB
    bf16_t* ctx = qb;                               // qb dead after QKV gemm
    float*  xf  = (float*)Qp;                       // 16 MB over Qp+Kp
    bf16_t* xb  = Vp;                               // Vp dead after attn

    dim3 blk(256);
    cvt_all_kernel<<<20480, blk, 0, stream>>>(q, kv, Wq, Wk, Wv, Wm, Wf1, Wf2,
                                              qb, Wqkvb, Wf1b);
    pack3_kernel<<<4, blk, 0, stream>>>(bQ, bK, bV, bqkv);

    bias_mlp_mfma<<<8192, blk, 0, stream>>>(amap, Wc1, bc1, Wc2, bc2, biasb);

    // fused QKV projection: 256^2 8-phase, N=3072 (192 blocks)
    gemm8p<3, false><<<192, dim3(512), 0, stream>>>(qb, kvb, Wqkvb, bqkv, Qp,
                                                    4096, 3072, 1024, 1024);

    attn_kernel<<<1024, blk, 0, stream>>>(Qp, Kp, Vp, biasb, ctx);

    // out-proj, split-K=2 -> bf16 partials p0,p1 (biasb region, dead now)
    gemm_bt<0, true><<<dim3(256, 2), blk, 0, stream>>>(ctx, nullptr, Wmb, bM, p0,
                                                       4096, 1024, 512, 1024);
    add_ln3_kernel<<<4096, blk, 0, stream>>>(q, p0, p1, g1, b1, xf, xb);

    // FFN1 (relu, bf16): 256^2 8-phase, N=4096 (256 blocks)
    gemm8p<2, false><<<256, dim3(512), 0, stream>>>(xb, nullptr, Wf1b, bf1, hb,
                                                    4096, 4096, 1024, 1024);
    // FFN2: 256^2 8-phase split-K=4 -> bf16 partials f0..f3 (64x4 = 256 blocks)
    gemm8p<0, true><<<dim3(64, 4), dim3(512), 0, stream>>>(hb, nullptr, Wf2b, bf2, f0,
                                                           4096, 1024, 1024, 4096);
    add_ln5_kernel<<<4096, blk, 0, stream>>>(xf, f0, f0 + 4194304, f0 + 8388608,
                                             f0 + 12582912, g2, b2, (float*)d_out, nullptr);
}

// Round 14
// 312.001 us; speedup vs baseline: 1.1325x; 1.0243x over previous
//
#include <hip/hip_runtime.h>
#include <hip/hip_bf16.h>

typedef __bf16 bf16_t;
typedef __bf16 bf16x4_t __attribute__((ext_vector_type(4)));
typedef __bf16 bf16x8_t __attribute__((ext_vector_type(8)));
typedef float  f32x4_t  __attribute__((ext_vector_type(4)));

#define B_   8
#define LQ_  512
#define LKV_ 512
#define D_   1024
#define H_   16
#define DH_  64
#define FF_  4096

__device__ __forceinline__ f32x4_t mfma16(bf16x8_t a, bf16x8_t b, f32x4_t c) {
    return __builtin_amdgcn_mfma_f32_16x16x32_bf16(a, b, c, 0, 0, 0);
}

__device__ __forceinline__ void gload_lds16(const bf16_t* g, bf16_t* l) {
    __builtin_amdgcn_global_load_lds(
        (const __attribute__((address_space(1))) void*)g,
        (__attribute__((address_space(3))) void*)l, 16, 0, 0);
}

// bijective XCD chunking (requires nwg % 8 == 0)
__device__ __forceinline__ int xcd_swz(int pid, int nwg) {
    return (pid & 7) * (nwg >> 3) + (pid >> 3);
}

// fast GELU: h * sigmoid(1.702 h).
__device__ __forceinline__ float gelu_fast(float h) {
    const float e = exp2f(h * -2.45546696f);     // exp(-1.702 h)
    return h * __builtin_amdgcn_rcpf(1.f + e);
}

// ---------------------------------------------------------------------------
// fused f32 -> bf16 convert for all 8 tensors + qkv-bias pack (one launch).
// grid 20483: blocks [0,20480) convert; last 3 blocks pack bQ|bK|bV -> bqkv.
// ---------------------------------------------------------------------------
__global__ __launch_bounds__(256)
void cvt_all_kernel(const float* __restrict__ q,  const float* __restrict__ kv,
                    const float* __restrict__ Wq, const float* __restrict__ Wk,
                    const float* __restrict__ Wv, const float* __restrict__ Wm,
                    const float* __restrict__ Wf1,const float* __restrict__ Wf2,
                    const float* __restrict__ bQ, const float* __restrict__ bK,
                    const float* __restrict__ bV, float* __restrict__ bqkv,
                    bf16_t* __restrict__ dq, bf16_t* __restrict__ dW,
                    bf16_t* __restrict__ dF) {
    const int i = blockIdx.x * 256 + threadIdx.x;    // float4 index
    if (i >= 5242880) {                              // bias pack (768 float4)
        const int j4 = i - 5242880;
        if (j4 < 768) {
            const float* s = (j4 < 256) ? bQ : (j4 < 512) ? bK : bV;
            const int jj = j4 & 255;
            ((float4*)bqkv)[j4] = ((const float4*)s)[jj];
        }
        return;
    }
    const float* s; bf16_t* d; int j;
    if (i < 1048576)      { s = q;   d = dq;           j = i; }
    else if (i < 2097152) { s = kv;  d = dq + 4194304; j = i - 1048576; }
    else if (i < 2359296) { s = Wq;  d = dW;           j = i - 2097152; }
    else if (i < 2621440) { s = Wk;  d = dW + 1048576; j = i - 2359296; }
    else if (i < 2883584) { s = Wv;  d = dW + 2097152; j = i - 2621440; }
    else if (i < 3145728) { s = Wm;  d = dW + 3145728; j = i - 2883584; }
    else if (i < 4194304) { s = Wf1; d = dF;           j = i - 3145728; }
    else                  { s = Wf2; d = dF + 4194304; j = i - 4194304; }
    const float4 v = ((const float4*)s)[j];
    bf16x4_t o;
    o[0] = (bf16_t)v.x; o[1] = (bf16_t)v.y; o[2] = (bf16_t)v.z; o[3] = (bf16_t)v.w;
    ((bf16x4_t*)d)[j] = o;
}

// ---------------------------------------------------------------------------
// AttentionBiasMLP via MFMA (323us-proven version: inline log2, 32KB LDS).
// Transcendental/latency-bound -- near its floor; do not touch (r11/r12 data).
// ---------------------------------------------------------------------------
__global__ __launch_bounds__(256)
void bias_mlp_mfma(const float* __restrict__ amap,
                   const float* __restrict__ Wc1, const float* __restrict__ bc1,
                   const float* __restrict__ Wc2, const float* __restrict__ bc2,
                   bf16_t* __restrict__ biasb) {
    __shared__ __align__(16) char lds[4][8192];
    const int t = threadIdx.x, lane = t & 63, w = t >> 6;
    const int l15 = lane & 15, lg = lane >> 4;
    char* Xs = lds[w];
    char* Hs = lds[w] + 3072;

    bf16x8_t b1f[2], b2f;
    f32x4_t bc1v[2];
#pragma unroll
    for (int ot = 0; ot < 2; ot++) {
        bf16x8_t v;
#pragma unroll
        for (int i = 0; i < 8; i++) {
            const int kk = (lg * 8 + i) & 15;
            const float wv = Wc1[(ot * 16 + l15) * 16 + kk] * 0.69314718055994531f;
            v[i] = (lg < 2) ? (bf16_t)wv : (bf16_t)0.f;
        }
        b1f[ot] = v;
        const float bb = bc1[ot * 16 + l15];
        bc1v[ot] = f32x4_t{bb, bb, bb, bb};
    }
    {
        bf16x8_t v;
#pragma unroll
        for (int i = 0; i < 8; i++) v[i] = (bf16_t)Wc2[l15 * 32 + lg * 8 + i];
        b2f = v;
    }
    const float bc2s = bc2[l15];
    const f32x4_t cinit2 = f32x4_t{bc2s, bc2s, bc2s, bc2s};

    const int posb = (blockIdx.x * 4 + w) * 64;
    const int b  = posb >> 18;
    const int q  = (posb >> 9) & 511;
    const int k0 = posb & 511;

    const float* src = amap + (size_t)(b * 16) * 263169 + (size_t)(q + 1) * 513 + (k0 + 1 + lane);
    bf16_t xr[16];
#pragma unroll
    for (int c = 0; c < 16; c++) {
        const float v = src[(size_t)c * 263169];
        xr[c] = (bf16_t)__log2f(v + 1e-6f);
    }
    *(bf16x8_t*)(Xs + lane * 48)      = *(bf16x8_t*)&xr[0];
    *(bf16x8_t*)(Xs + lane * 48 + 16) = *(bf16x8_t*)&xr[8];

    const int lgm16 = (lg & 1) * 16;
    f32x4_t h1[4][2];
#pragma unroll
    for (int p = 0; p < 4; p++) {
        const bf16x8_t a1 = *(const bf16x8_t*)(Xs + (p * 16 + l15) * 48 + lgm16);
#pragma unroll
        for (int ot = 0; ot < 2; ot++)
            h1[p][ot] = mfma16(a1, b1f[ot], bc1v[ot]);
    }

#pragma unroll
    for (int p = 0; p < 4; p++)
#pragma unroll
        for (int ot = 0; ot < 2; ot++)
#pragma unroll
            for (int r = 0; r < 4; r++) {
                const float g = gelu_fast(h1[p][ot][r]);
                *(bf16_t*)(Hs + (p * 16 + lg * 4 + r) * 80 + (ot * 16 + l15) * 2) = (bf16_t)g;
            }

    const size_t obase = ((size_t)(b * 16 + l15) * 512 + q) * 512 + k0;
#pragma unroll
    for (int p = 0; p < 4; p++) {
        const bf16x8_t a2 = *(const bf16x8_t*)(Hs + (p * 16 + l15) * 80 + lg * 16);
        const f32x4_t o2 = mfma16(a2, b2f, cinit2);
        bf16x4_t ov;
#pragma unroll
        for (int r = 0; r < 4; r++) ov[r] = (bf16_t)o2[r];
        *(bf16x4_t*)&biasb[obase + p * 16 + lg * 4] = ov;
    }
}

// ---------------------------------------------------------------------------
// 128^2 bf16 GEMM (3-slot pipeline) -- out-proj (N=1024).
// LDS chunk-swizzle s(r)=r&3 both-sides.
// ---------------------------------------------------------------------------
template <int EPI, bool SPLIT>
__global__ __launch_bounds__(256)
void gemm_bt(const bf16_t* __restrict__ A, const bf16_t* __restrict__ A2,
             const bf16_t* __restrict__ Bw,
             const float* __restrict__ bias,
             bf16_t* __restrict__ Cb, int M, int N, int Klen, int lda) {
    __shared__ __align__(16) bf16_t As[3][128 * 32];
    __shared__ __align__(16) bf16_t Bs[3][128 * 32];
    const int t = threadIdx.x, lane = t & 63, w = t >> 6;
    const int wr = w >> 1, wc = w & 1;
    const int ntn = N >> 7;
    const int nwg = (M >> 7) * ntn;
    const int wg  = xcd_swz((int)blockIdx.x, nwg);
    const int gsz = 8 * ntn;
    const int gid = wg / gsz;
    const int rem = wg - gid * gsz;
    const int tm  = gid * 8 + (rem & 7);
    const int tn  = rem >> 3;
    const int l15 = lane & 15, lg = lane >> 4;
    const int ks = SPLIT ? blockIdx.y : 0;
    const int koff = SPLIT ? ks * Klen : 0;

    const int r0 = t >> 2,          sk0 = (t & 3) ^ ((t >> 2) & 3);
    const int r1 = (t + 256) >> 2,  sk1 = (t & 3) ^ ((t >> 2) & 3);
    const int b0 = (w * 64) * 8;
    const int b1 = (256 + w * 64) * 8;
    const bf16_t* Abase0 = A  + (size_t)(tm * 128 + r0) * lda + koff + sk0 * 8;
    const bf16_t* Abase1 = A  + (size_t)(tm * 128 + r1) * lda + koff + sk1 * 8;
    const bf16_t* Bbase0 = Bw + (size_t)(tn * 128 + r0) * lda + koff + sk0 * 8;
    const bf16_t* Bbase1 = Bw + (size_t)(tn * 128 + r1) * lda + koff + sk1 * 8;

    f32x4_t acc[4][4];
#pragma unroll
    for (int i = 0; i < 4; i++)
#pragma unroll
        for (int j = 0; j < 4; j++) acc[i][j] = f32x4_t{0.f, 0.f, 0.f, 0.f};

    const int nk = Klen >> 5;

#define STAGE128(KT, S)                                 \
    do {                                                \
        const int _ko = (KT) * 32;                      \
        gload_lds16(Abase0 + _ko, &As[(S)][b0]);        \
        gload_lds16(Abase1 + _ko, &As[(S)][b1]);        \
        gload_lds16(Bbase0 + _ko, &Bs[(S)][b0]);        \
        gload_lds16(Bbase1 + _ko, &Bs[(S)][b1]);        \
    } while (0)

    STAGE128(0, 0);
    STAGE128(1, 1);

    const int rsw = l15 & 3;           // read-side row&3
    int cur = 0;
    for (int kt = 0; kt < nk; ++kt) {
        if (kt + 1 < nk) { asm volatile("s_waitcnt vmcnt(4)" ::: "memory"); }
        else             { asm volatile("s_waitcnt vmcnt(0)" ::: "memory"); }
        __syncthreads();
        if (kt + 2 < nk) {
            const int s2 = cur >= 1 ? cur - 1 : cur + 2;
            STAGE128(kt + 2, s2);
        }

        const bf16_t* Ac = As[cur];
        const bf16_t* Bc = Bs[cur];
        bf16x8_t af[4], bfv[4];
#pragma unroll
        for (int mt = 0; mt < 4; mt++)
            af[mt] = *(const bf16x8_t*)&Ac[(wr * 64 + mt * 16 + l15) * 32 + ((lg ^ rsw) * 8)];
#pragma unroll
        for (int nt = 0; nt < 4; nt++)
            bfv[nt] = *(const bf16x8_t*)&Bc[(wc * 64 + nt * 16 + l15) * 32 + ((lg ^ rsw) * 8)];
#pragma unroll
        for (int mt = 0; mt < 4; mt++)
#pragma unroll
            for (int nt = 0; nt < 4; nt++)
                acc[mt][nt] = mfma16(af[mt], bfv[nt], acc[mt][nt]);

        cur = cur < 2 ? cur + 1 : 0;
    }
#undef STAGE128

#pragma unroll
    for (int nt = 0; nt < 4; nt++) {
        const int col = tn * 128 + wc * 64 + nt * 16 + l15;
        float bv = bias[col];
        if (SPLIT && ks != 0) bv = 0.f;
#pragma unroll
        for (int mt = 0; mt < 4; mt++) {
#pragma unroll
            for (int r = 0; r < 4; r++) {
                const int row = tm * 128 + wr * 64 + mt * 16 + lg * 4 + r;
                float v = acc[mt][nt][r] + bv;
                if (EPI == 2) v = fmaxf(v, 0.f);
                if (SPLIT)
                    Cb[(size_t)ks * M * N + (size_t)row * N + col] = (bf16_t)v;
                else Cb[(size_t)row * N + col] = (bf16_t)v;
            }
        }
    }
}

// ---------------------------------------------------------------------------
// 256^2 BK=64 8-wave phase-split GEMM.  LDS chunk-swizzle s(r)=r&7 both-sides.
// EPI: 0 = plain bf16 (split partial), 2 = relu bf16 (FFN1), 3 = QKV fused.
// SPLIT: blockIdx.y = K-slice; partials at Cb + ks*M*N; bias on ks==0 only.
// ---------------------------------------------------------------------------
template <int EPI, bool SPLIT>
__global__ __launch_bounds__(512, 1)
void gemm8p(const bf16_t* __restrict__ A, const bf16_t* __restrict__ A2,
            const bf16_t* __restrict__ Bw, const float* __restrict__ bias,
            bf16_t* __restrict__ Cb, int M, int N, int Klen, int lda) {
    __shared__ __align__(16) bf16_t As[2][256 * 64];   // 32 KB per buffer
    __shared__ __align__(16) bf16_t Bs[2][256 * 64];   // total LDS 128 KB
    const int t = threadIdx.x, lane = t & 63, w = t >> 6;     // 8 waves
    const int wr = w >> 2, wc = w & 3;                        // 2 x 4 wave grid
    const int l15 = lane & 15, lg = lane >> 4;
    const int ntn = N >> 8;
    const int nwg = (M >> 8) * ntn;
    const int wg  = xcd_swz((int)blockIdx.x, nwg);
    const int gsz = 8 * ntn;
    const int gid = wg / gsz;
    const int rem = wg - gid * gsz;
    const int tm  = gid * 8 + (rem & 7);
    const int tn  = rem >> 3;
    const int ks   = SPLIT ? blockIdx.y : 0;
    const int koff = SPLIT ? ks * Klen : 0;
    if (EPI == 3 && tn >= 4) A = A2;    // cols >= 1024 use kv input

    const int srow = w * 8 + (lane >> 3);
    const int scol = ((lane & 7) ^ (lane >> 3)) * 8;
    const bf16_t* Ag = A  + (size_t)(tm * 256 + srow) * lda + koff + scol;
    const bf16_t* Bg = Bw + (size_t)(tn * 256 + srow) * lda + koff + scol;
    const int ldsb = w * 512;

#define STAGE256(KT, S)                                                      \
    do {                                                                     \
        const size_t _ko = (size_t)(KT) * 64;                                \
        _Pragma("unroll")                                                    \
        for (int _i = 0; _i < 4; _i++) {                                     \
            gload_lds16(Ag + (size_t)(_i * 64) * lda + _ko,                  \
                        &As[(S)][_i * 4096 + ldsb]);                         \
            gload_lds16(Bg + (size_t)(_i * 64) * lda + _ko,                  \
                        &Bs[(S)][_i * 4096 + ldsb]);                         \
        }                                                                    \
    } while (0)

    f32x4_t acc[8][4];
#pragma unroll
    for (int i = 0; i < 8; i++)
#pragma unroll
        for (int j = 0; j < 4; j++) acc[i][j] = f32x4_t{0.f, 0.f, 0.f, 0.f};

    const int nk = Klen >> 6;

    STAGE256(0, 0);
    STAGE256(1, 1);

    const int rsw = l15 & 7;           // read-side row&7
    for (int kt = 0; kt < nk; ++kt) {
        const int s = kt & 1;
        if (kt + 1 < nk) { asm volatile("s_waitcnt vmcnt(8)" ::: "memory"); }
        else             { asm volatile("s_waitcnt vmcnt(0)" ::: "memory"); }
        __builtin_amdgcn_s_barrier();            // barrier A: tile kt visible
        __builtin_amdgcn_sched_barrier(0);

#pragma unroll
        for (int q = 0; q < 4; q++) {            // quadrant (mh, nh)
            const int mh = q >> 1, nh = q & 1;
            bf16x8_t af[4][2], bfv[2][2];
#pragma unroll
            for (int mi = 0; mi < 4; mi++) {
                const int row = wr * 128 + (mh * 4 + mi) * 16 + l15;
#pragma unroll
                for (int kk = 0; kk < 2; kk++)
                    af[mi][kk] = *(const bf16x8_t*)&As[s][row * 64 + (((kk * 4 + lg) ^ rsw) * 8)];
            }
#pragma unroll
            for (int ni = 0; ni < 2; ni++) {
                const int row = wc * 64 + (nh * 2 + ni) * 16 + l15;
#pragma unroll
                for (int kk = 0; kk < 2; kk++)
                    bfv[ni][kk] = *(const bf16x8_t*)&Bs[s][row * 64 + (((kk * 4 + lg) ^ rsw) * 8)];
            }
            __builtin_amdgcn_s_setprio(1);
#pragma unroll
            for (int mi = 0; mi < 4; mi++)
#pragma unroll
                for (int ni = 0; ni < 2; ni++)
#pragma unroll
                    for (int kk = 0; kk < 2; kk++)
                        acc[mh * 4 + mi][nh * 2 + ni] =
                            mfma16(af[mi][kk], bfv[ni][kk], acc[mh * 4 + mi][nh * 2 + ni]);
            __builtin_amdgcn_s_setprio(0);
        }

        __builtin_amdgcn_sched_barrier(0);
        __builtin_amdgcn_s_barrier();            // barrier B: all reads retired
        __builtin_amdgcn_sched_barrier(0);
        if (kt + 2 < nk) STAGE256(kt + 2, s);    // refill freed buffer
    }
#undef STAGE256

    // epilogue
#pragma unroll
    for (int n = 0; n < 4; n++) {
        const int col = tn * 256 + wc * 64 + n * 16 + l15;
        float bv = bias[col];
        if (SPLIT && ks != 0) bv = 0.f;
#pragma unroll
        for (int m = 0; m < 8; m++) {
#pragma unroll
            for (int r = 0; r < 4; r++) {
                const int row = tm * 256 + wr * 128 + m * 16 + lg * 4 + r;
                float v = acc[m][n][r] + bv;
                if (EPI == 2) v = fmaxf(v, 0.f);
                if (EPI == 3 && tn < 4) v *= 0.125f;
                if (SPLIT)
                    Cb[(size_t)ks * M * N + (size_t)row * N + col] = (bf16_t)v;
                else if (EPI == 3)
                    Cb[(size_t)(col >> 10) * 4194304 + (size_t)row * 1024 + (col & 1023)] = (bf16_t)v;
                else
                    Cb[(size_t)row * N + col] = (bf16_t)v;
            }
        }
    }
}

// ---------------------------------------------------------------------------
// Flash attention with additive bias (unchanged from the 319us config).
// ---------------------------------------------------------------------------
__global__ __launch_bounds__(256)
void attn_kernel(const bf16_t* __restrict__ Qp, const bf16_t* __restrict__ Kp,
                 const bf16_t* __restrict__ Vp, const bf16_t* __restrict__ biasb,
                 bf16_t* __restrict__ ctx) {
    __shared__ __align__(16) bf16_t Qs[64 * 64];
    __shared__ __align__(16) bf16_t Ks[64 * 64];
    __shared__ __align__(16) bf16_t Vts[64 * 64];
    __shared__ __align__(16) bf16_t Ps[64 * 64];
    __shared__ __align__(16) bf16_t Bbs[64 * 64];

    const int bid = xcd_swz((int)blockIdx.x, 1024);
    const int qt = bid & 7, h = (bid >> 3) & 15, b = bid >> 7;
    const int t = threadIdx.x, lane = t & 63, w = t >> 6;
    const int l15 = lane & 15, lg = lane >> 4;

#pragma unroll
    for (int i = 0; i < 2; i++) {
        const int c = t + i * 256;
        const int row = c >> 3, cg = c & 7;
        const uint4 v = *(const uint4*)&Qp[(((size_t)(b * LQ_ + qt * 64 + row)) * H_ + h) * DH_ + cg * 8];
        *(uint4*)((char*)Qs + row * 128 + ((cg ^ (row & 7)) << 4)) = v;
    }
    __syncthreads();

    bf16x8_t aq[2];
    {
        const int rowq = w * 16 + l15;
#pragma unroll
        for (int kc = 0; kc < 2; kc++)
            aq[kc] = *(const bf16x8_t*)((const char*)Qs + rowq * 128 + (((kc * 4 + lg) ^ (rowq & 7)) << 4));
    }

    f32x4_t oacc[4];
#pragma unroll
    for (int i = 0; i < 4; i++) oacc[i] = f32x4_t{0.f, 0.f, 0.f, 0.f};
    float mrow[4] = {-1e30f, -1e30f, -1e30f, -1e30f};
    float lrow[4] = {0.f, 0.f, 0.f, 0.f};

    const bf16_t* bias_tile = biasb + ((size_t)(b * H_ + h) * LQ_ + qt * 64) * LKV_;

    for (int kt = 0; kt < 8; ++kt) {
        __syncthreads();
#pragma unroll
        for (int i = 0; i < 2; i++) {
            const int c = t + i * 256;
            const int row = c >> 3, cg = c & 7;
            const uint4 v = *(const uint4*)&Kp[(((size_t)(b * LKV_ + kt * 64 + row)) * H_ + h) * DH_ + cg * 8];
            *(uint4*)((char*)Ks + row * 128 + ((cg ^ (row & 7)) << 4)) = v;
        }
#pragma unroll
        for (int i = 0; i < 2; i++) {
            const int c = t + i * 256;
            const int row = c >> 3, cg = c & 7;
            const uint4 bv4 = *(const uint4*)&bias_tile[(size_t)row * LKV_ + kt * 64 + cg * 8];
            *(uint4*)&Bbs[row * 64 + cg * 8] = bv4;
        }
#pragma unroll
        for (int i = 0; i < 2; i++) {
            const int c = t + i * 256;
            const int k = c >> 3, dg = c & 7;
            const bf16x8_t vv = *(const bf16x8_t*)&Vp[(((size_t)(b * LKV_ + kt * 64 + k)) * H_ + h) * DH_ + dg * 8];
#pragma unroll
            for (int j = 0; j < 8; j++) {
                const int d = dg * 8 + j;
                *(bf16_t*)((char*)Vts + d * 128 + ((((k * 2) >> 4) ^ (d & 7)) << 4) + ((k * 2) & 15)) = vv[j];
            }
        }
        __syncthreads();

        f32x4_t sacc[4];
#pragma unroll
        for (int i = 0; i < 4; i++) sacc[i] = f32x4_t{0.f, 0.f, 0.f, 0.f};
#pragma unroll
        for (int nt = 0; nt < 4; nt++) {
            const int rowk = nt * 16 + l15;
#pragma unroll
            for (int kc = 0; kc < 2; kc++) {
                const bf16x8_t bk = *(const bf16x8_t*)((const char*)Ks + rowk * 128 + (((kc * 4 + lg) ^ (rowk & 7)) << 4));
                sacc[nt] = mfma16(aq[kc], bk, sacc[nt]);
            }
        }

        float esc[4];
#pragma unroll
        for (int r = 0; r < 4; r++) {
            const int qr = w * 16 + lg * 4 + r;
            float mx = -1e30f;
#pragma unroll
            for (int nt = 0; nt < 4; nt++) {
                const float bvv = (float)Bbs[qr * 64 + nt * 16 + l15];
                const float v = sacc[nt][r] + bvv;
                sacc[nt][r] = v;
                mx = fmaxf(mx, v);
            }
#pragma unroll
            for (int msk = 8; msk >= 1; msk >>= 1) mx = fmaxf(mx, __shfl_xor(mx, msk));
            const float mnew = fmaxf(mrow[r], mx);
            esc[r] = __expf(mrow[r] - mnew);
            mrow[r] = mnew;
            float rs = 0.f;
#pragma unroll
            for (int nt = 0; nt < 4; nt++) {
                const float p = __expf(sacc[nt][r] - mnew);
                sacc[nt][r] = p;
                rs += p;
            }
#pragma unroll
            for (int msk = 8; msk >= 1; msk >>= 1) rs += __shfl_xor(rs, msk);
            lrow[r] = lrow[r] * esc[r] + rs;
        }

#pragma unroll
        for (int r = 0; r < 4; r++) {
            const int prow = w * 16 + lg * 4 + r;
#pragma unroll
            for (int nt = 0; nt < 4; nt++) {
                const int pc2 = (nt * 16 + l15) * 2;
                *(bf16_t*)((char*)Ps + prow * 128 + (((pc2 >> 4) ^ (prow & 7)) << 4) + (pc2 & 15)) =
                    (bf16_t)sacc[nt][r];
            }
        }
        asm volatile("s_waitcnt lgkmcnt(0)" ::: "memory");
        __builtin_amdgcn_sched_barrier(0);

#pragma unroll
        for (int dt = 0; dt < 4; dt++)
#pragma unroll
            for (int r = 0; r < 4; r++) oacc[dt][r] *= esc[r];

        bf16x8_t pa[2];
        {
            const int rowp = w * 16 + l15;
#pragma unroll
            for (int kc = 0; kc < 2; kc++)
                pa[kc] = *(const bf16x8_t*)((const char*)Ps + rowp * 128 + (((kc * 4 + lg) ^ (rowp & 7)) << 4));
        }
#pragma unroll
        for (int dt = 0; dt < 4; dt++) {
            const int rowv = dt * 16 + l15;
#pragma unroll
            for (int kc = 0; kc < 2; kc++) {
                const bf16x8_t bv = *(const bf16x8_t*)((const char*)Vts + rowv * 128 + (((kc * 4 + lg) ^ (rowv & 7)) << 4));
                oacc[dt] = mfma16(pa[kc], bv, oacc[dt]);
            }
        }
    }

    float inv[4];
#pragma unroll
    for (int r = 0; r < 4; r++) inv[r] = __builtin_amdgcn_rcpf(lrow[r]);
#pragma unroll
    for (int dt = 0; dt < 4; dt++) {
#pragma unroll
        for (int r = 0; r < 4; r++) {
            const float v = oacc[dt][r] * inv[r];
            const int q = qt * 64 + w * 16 + lg * 4 + r;
            const int d = dt * 16 + l15;
            ctx[(((size_t)(b * LQ_ + q)) * H_ + h) * DH_ + d] = (bf16_t)v;
        }
    }
}

// ---------------------------------------------------------------------------
// mid-LN: out_bf16 = LayerNorm(Xb + Y0 + Y1) * g + b.  All-bf16 inputs.
// ---------------------------------------------------------------------------
__global__ __launch_bounds__(256)
void add_ln3_mid_kernel(const bf16_t* __restrict__ Xb, const bf16_t* __restrict__ Y0,
                        const bf16_t* __restrict__ Y1,
                        const float* __restrict__ g, const float* __restrict__ be,
                        bf16_t* __restrict__ ob) {
    const int row = blockIdx.x, t = threadIdx.x;
    const bf16x4_t xv = ((const bf16x4_t*)(Xb + (size_t)row * 1024))[t];
    const bf16x4_t y0 = ((const bf16x4_t*)(Y0 + (size_t)row * 1024))[t];
    const bf16x4_t y1 = ((const bf16x4_t*)(Y1 + (size_t)row * 1024))[t];
    float v[4];
#pragma unroll
    for (int i = 0; i < 4; i++)
        v[i] = (float)xv[i] + (float)y0[i] + (float)y1[i];
    float s = v[0] + v[1] + v[2] + v[3];
    float s2 = v[0] * v[0] + v[1] * v[1] + v[2] * v[2] + v[3] * v[3];
#pragma unroll
    for (int m = 32; m >= 1; m >>= 1) { s += __shfl_xor(s, m); s2 += __shfl_xor(s2, m); }
    __shared__ float red[8];
    const int w = t >> 6, lane = t & 63;
    if (lane == 0) { red[w] = s; red[4 + w] = s2; }
    __syncthreads();
    s = red[0] + red[1] + red[2] + red[3];
    s2 = red[4] + red[5] + red[6] + red[7];
    const float mu = s * (1.f / 1024.f);
    const float var = s2 * (1.f / 1024.f) - mu * mu;
    const float rstd = rsqrtf(var + 1e-6f);
    const float4 gv = ((const float4*)g)[t];
    const float4 bv = ((const float4*)be)[t];
    bf16x4_t qo;
    qo[0] = (bf16_t)((v[0] - mu) * rstd * gv.x + bv.x);
    qo[1] = (bf16_t)((v[1] - mu) * rstd * gv.y + bv.y);
    qo[2] = (bf16_t)((v[2] - mu) * rstd * gv.z + bv.z);
    qo[3] = (bf16_t)((v[3] - mu) * rstd * gv.w + bv.w);
    ((bf16x4_t*)(ob + (size_t)row * 1024))[t] = qo;
}

// ---------------------------------------------------------------------------
// final LN: out_f32 = LayerNorm(Xb + Y0+Y1+Y2+Y3) * g + b.
// ---------------------------------------------------------------------------
__global__ __launch_bounds__(256)
void add_ln5_fin_kernel(const bf16_t* __restrict__ Xb, const bf16_t* __restrict__ Y0,
                        const bf16_t* __restrict__ Y1, const bf16_t* __restrict__ Y2,
                        const bf16_t* __restrict__ Y3,
                        const float* __restrict__ g, const float* __restrict__ be,
                        float* __restrict__ of) {
    const int row = blockIdx.x, t = threadIdx.x;
    const bf16x4_t xv = ((const bf16x4_t*)(Xb + (size_t)row * 1024))[t];
    const bf16x4_t y0 = ((const bf16x4_t*)(Y0 + (size_t)row * 1024))[t];
    const bf16x4_t y1 = ((const bf16x4_t*)(Y1 + (size_t)row * 1024))[t];
    const bf16x4_t y2 = ((const bf16x4_t*)(Y2 + (size_t)row * 1024))[t];
    const bf16x4_t y3 = ((const bf16x4_t*)(Y3 + (size_t)row * 1024))[t];
    float v[4];
#pragma unroll
    for (int i = 0; i < 4; i++)
        v[i] = (float)xv[i] + ((float)y0[i] + (float)y1[i]) + ((float)y2[i] + (float)y3[i]);
    float s = v[0] + v[1] + v[2] + v[3];
    float s2 = v[0] * v[0] + v[1] * v[1] + v[2] * v[2] + v[3] * v[3];
#pragma unroll
    for (int m = 32; m >= 1; m >>= 1) { s += __shfl_xor(s, m); s2 += __shfl_xor(s2, m); }
    __shared__ float red[8];
    const int w = t >> 6, lane = t & 63;
    if (lane == 0) { red[w] = s; red[4 + w] = s2; }
    __syncthreads();
    s = red[0] + red[1] + red[2] + red[3];
    s2 = red[4] + red[5] + red[6] + red[7];
    const float mu = s * (1.f / 1024.f);
    const float var = s2 * (1.f / 1024.f) - mu * mu;
    const float rstd = rsqrtf(var + 1e-6f);
    const float4 gv = ((const float4*)g)[t];
    const float4 bv = ((const float4*)be)[t];
    float o[4];
    o[0] = (v[0] - mu) * rstd * gv.x + bv.x;
    o[1] = (v[1] - mu) * rstd * gv.y + bv.y;
    o[2] = (v[2] - mu) * rstd * gv.z + bv.z;
    o[3] = (v[3] - mu) * rstd * gv.w + bv.w;
    ((float4*)(of + (size_t)row * 1024))[t] = make_float4(o[0], o[1], o[2], o[3]);
}

// ---------------------------------------------------------------------------
extern "C" void kernel_launch(void* const* d_in, const int* in_sizes, int n_in,
                              void* d_out, int out_size, void* d_ws, size_t ws_size,
                              hipStream_t stream) {
    (void)in_sizes; (void)n_in; (void)out_size; (void)ws_size;
    const float* q    = (const float*)d_in[0];
    const float* kv   = (const float*)d_in[1];
    const float* amap = (const float*)d_in[2];
    const float* Wq = (const float*)d_in[3];  const float* bQ = (const float*)d_in[4];
    const float* Wk = (const float*)d_in[5];  const float* bK = (const float*)d_in[6];
    const float* Wv = (const float*)d_in[7];  const float* bV = (const float*)d_in[8];
    const float* Wm = (const float*)d_in[9];  const float* bM = (const float*)d_in[10];
    const float* Wc1 = (const float*)d_in[11]; const float* bc1 = (const float*)d_in[12];
    const float* Wc2 = (const float*)d_in[13]; const float* bc2 = (const float*)d_in[14];
    const float* Wf1 = (const float*)d_in[15]; const float* bf1 = (const float*)d_in[16];
    const float* Wf2 = (const float*)d_in[17]; const float* bf2 = (const float*)d_in[18];
    const float* g1 = (const float*)d_in[19]; const float* b1 = (const float*)d_in[20];
    const float* g2 = (const float*)d_in[21]; const float* b2 = (const float*)d_in[22];

    char* w = (char*)d_ws;
    bf16_t* biasb = (bf16_t*)(w);                   // 64 MB, dead after attn
    bf16_t* p0    = (bf16_t*)(w);                   // 2x 8 MB partials (after attn)
    bf16_t* p1    = (bf16_t*)(w + 8388608);
    bf16_t* hb    = (bf16_t*)(w);                   // 32 MB (after add_ln mid)
    bf16_t* f0    = (bf16_t*)(w + 33554432);        // 4x 8 MB partials [33.5,67) MB
    bf16_t* qb   = (bf16_t*)(w + 67108864);         // 8 MB, live thru add_ln mid
    bf16_t* kvb  = (bf16_t*)(w + 75497472);         // 8 MB
    bf16_t* Qp   = (bf16_t*)(w + 83886080);         // 8 MB each, Q|K|V contiguous
    bf16_t* Kp   = (bf16_t*)(w + 92274688);
    bf16_t* Vp   = (bf16_t*)(w + 100663296);
    bf16_t* Wqkvb = (bf16_t*)(w + 109051904);       // 6 MB (Wq|Wk|Wv bf16)
    bf16_t* Wmb  = (bf16_t*)(w + 115343360);        // 2 MB
    bf16_t* Wf1b = (bf16_t*)(w + 117440512);        // 8 MB
    bf16_t* Wf2b = (bf16_t*)(w + 125829120);        // 8 MB
    float*  bqkv = (float*)(w + 134217728);         // 12 KB
    bf16_t* ctx  = (bf16_t*)(w + 150994944);        // 8 MB (own region; qb stays live)
    bf16_t* xb  = Vp;                               // LN1 output (Vp dead after attn)

    dim3 blk(256);
    cvt_all_kernel<<<20483, blk, 0, stream>>>(q, kv, Wq, Wk, Wv, Wm, Wf1, Wf2,
                                              bQ, bK, bV, bqkv, qb, Wqkvb, Wf1b);

    bias_mlp_mfma<<<8192, blk, 0, stream>>>(amap, Wc1, bc1, Wc2, bc2, biasb);

    // fused QKV projection: 256^2 8-phase, N=3072 (192 blocks)
    gemm8p<3, false><<<192, dim3(512), 0, stream>>>(qb, kvb, Wqkvb, bqkv, Qp,
                                                    4096, 3072, 1024, 1024);

    attn_kernel<<<1024, blk, 0, stream>>>(Qp, Kp, Vp, biasb, ctx);

    // out-proj, split-K=2 -> bf16 partials p0,p1 (biasb region, dead now)
    gemm_bt<0, true><<<dim3(256, 2), blk, 0, stream>>>(ctx, nullptr, Wmb, bM, p0,
                                                       4096, 1024, 512, 1024);
    // LN1: bf16 residual (qb) + partials -> xb (bf16; feeds FFN1 AND final LN)
    add_ln3_mid_kernel<<<4096, blk, 0, stream>>>(qb, p0, p1, g1, b1, xb);

    // FFN1 (relu, bf16): 256^2 8-phase, N=4096 (256 blocks)
    gemm8p<2, false><<<256, dim3(512), 0, stream>>>(xb, nullptr, Wf1b, bf1, hb,
                                                    4096, 4096, 1024, 1024);
    // FFN2: 256^2 8-phase split-K=4 -> bf16 partials f0..f3 (64x4 = 256 blocks)
    gemm8p<0, true><<<dim3(64, 4), dim3(512), 0, stream>>>(hb, nullptr, Wf2b, bf2, f0,
                                                           4096, 1024, 1024, 4096);
    add_ln5_fin_kernel<<<4096, blk, 0, stream>>>(xb, f0, f0 + 4194304, f0 + 8388608,
                                                 f0 + 12582912, g2, b2, (float*)d_out);
}